// Round 11
// baseline (190.527 us; speedup 1.0000x reference)
//
#include <hip/hip_runtime.h>
#include <math.h>

#define B_ 8
#define L_ 4096
#define DM 128
#define DI 256
#define DSN 16
#define RK 8
#define M_ (B_*L_)      // 32768 positions
#define NC 128          // number of scan chunks
#define CH 32           // chunk length (NC*CH == L_)
#define CH2 64          // fused phase3 tile: 2 chunks

typedef __attribute__((ext_vector_type(8))) short bfrag;   // 8 bf16 (4 VGPRs)
typedef __attribute__((ext_vector_type(4))) float ffrag;   // 4 fp32 acc
typedef __attribute__((ext_vector_type(2))) float f32x2;   // packed-math pair

__device__ __forceinline__ float silu_f(float x) {
  return x * __builtin_amdgcn_rcpf(1.f + __expf(-x));
}
__device__ __forceinline__ float softplus_f(float x) {
  return (x > 20.f) ? x : __logf(1.f + __expf(x));
}

__device__ __forceinline__ unsigned short f2bf(float f) {
  unsigned int u = __builtin_bit_cast(unsigned int, f);
  unsigned int r = (u + 0x7FFFu + ((u >> 16) & 1u)) >> 16;   // RNE
  return (unsigned short)r;
}
__device__ __forceinline__ unsigned int f2bf2(float lo, float hi) {
  return (unsigned int)f2bf(lo) | ((unsigned int)f2bf(hi) << 16);
}
__device__ __forceinline__ float bf2f(unsigned int us) {
  return __builtin_bit_cast(float, us << 16);
}

// ---------------------------------------------------------------------------
// One-shot weight prep: f32 -> bf16 (same RNE -> bit-identical), PLUS the
// composed dt matrix  M[d][k] = sum_{r<8} dtw[d][r] * xw[r][k]  (f32
// accumulate, then bf16). M lets x_proj's MFMA produce dt_raw directly,
// deleting the scan tail's 8-FMA dot (256 FMA + 64 LDS reads per thread).
// ---------------------------------------------------------------------------
__global__ __launch_bounds__(256)
void prep_weights(const float* __restrict__ w_in, const float* __restrict__ xw,
                  const float* __restrict__ ow, const float* __restrict__ fcw,
                  const float* __restrict__ dtw,
                  unsigned short* __restrict__ w_in_b, unsigned short* __restrict__ xw_b,
                  unsigned short* __restrict__ ow_b, unsigned short* __restrict__ fcw_b,
                  unsigned short* __restrict__ Mb) {
  const int i = blockIdx.x * 256 + threadIdx.x;
  if (i < 31232) {
    const float* src; unsigned short* dst; int j;
    if (i < 16384)      { src = w_in; dst = w_in_b; j = i; }           // 512x128
    else if (i < 18944) { src = xw;   dst = xw_b;   j = i - 16384; }   // 40x256
    else if (i < 27136) { src = ow;   dst = ow_b;   j = i - 18944; }   // 128x256
    else                { src = fcw;  dst = fcw_b;  j = i - 27136; }   // 128x128
    float4 v = *(const float4*)&src[j << 2];
    uint2 p = {f2bf2(v.x, v.y), f2bf2(v.z, v.w)};
    *(uint2*)&dst[j << 2] = p;
  } else if (i < 47616) {
    // M: 256x256, 4 outputs per thread
    const int j = i - 31232;          // 0..16383
    const int dch = j >> 6;           // 0..255
    const int k4 = (j & 63) << 2;     // 0..252
    float m0 = 0.f, m1 = 0.f, m2 = 0.f, m3 = 0.f;
#pragma unroll
    for (int r = 0; r < 8; ++r) {
      float wv = dtw[dch * 8 + r];
      const float* xr = &xw[r * 256 + k4];
      m0 = fmaf(wv, xr[0], m0);
      m1 = fmaf(wv, xr[1], m1);
      m2 = fmaf(wv, xr[2], m2);
      m3 = fmaf(wv, xr[3], m3);
    }
    uint2 p = {f2bf2(m0, m1), f2bf2(m2, m3)};
    *(uint2*)&Mb[dch * 256 + k4] = p;
  }
}

// ---------------------------------------------------------------------------
// MEGA-FUSED front end, r11: x_proj MFMA extended to 18 n-tiles
// (B,C from xw rows 8..39 + 16 dt-tiles from composed M). dt_raw gets
// bias+softplus in the MFMA epilogue, packed with u into udt (uint4 stores,
// 64B-sector aligned). Scan tail now reads udt back (L2-hot, prefetch-2)
// and runs just the recurrence (~25 inst/iter vs ~34; dtr_s/dtw deleted).
// LDS pool 36.6 KB: [As|ua 16.9K][hx 18.5K][Bs_l 2K]  -> 4 blocks/CU.
// ---------------------------------------------------------------------------
__global__ __launch_bounds__(256, 4)
void xproj_dtproj(const float* __restrict__ s, const unsigned short* __restrict__ w_in_b,
                  const unsigned short* __restrict__ xw_b,
                  const unsigned short* __restrict__ Mb,
                  const float* __restrict__ dtpb,
                  const float* __restrict__ cw, const float* __restrict__ cb,
                  const float* __restrict__ alog,
                  float* __restrict__ Bb, float* __restrict__ Cb,
                  unsigned int* __restrict__ udt,
                  unsigned short* __restrict__ zsb,
                  unsigned short* __restrict__ cP, unsigned short* __restrict__ cHe) {
  __shared__ __align__(16) char pool[37424];
  unsigned short* As = (unsigned short*)pool;              // 48*136*2 = 13056
  unsigned short* ua = (unsigned short*)pool;              // 32*264*2 = 16896 (overlay As)
  unsigned short* hx = (unsigned short*)(pool + 16896);    // 35*264*2 = 18480
  float* Bs_l  = (float*)(pool + 35376);                   // 32*16*4  = 2048
  const int t = threadIdx.x;
  const int p0 = blockIdx.x << 5;             // 32-position tile = one chunk
  const int w = t >> 6, l = t & 63, q = l >> 4, col = l & 15;

  // ---- stage A (32 main rows + 16 halo rows of s, f32 -> bf16) ----
  for (int i = t; i < 48 * 32; i += 256) {
    int row = i >> 5, c4 = i & 31;
    int pos = (row < 32) ? (p0 + row) : (p0 - 16 + (row - 32));
    if (pos < 0) pos = 0;                     // block 0 halo: clamped, masked later
    float4 av = *(const float4*)&s[pos * 128 + (c4 << 2)];
    uint2 ap = {f2bf2(av.x, av.y), f2bf2(av.z, av.w)};
    *(uint2*)&As[row * 136 + (c4 << 2)] = ap;
  }
  __syncthreads();
  // ---- in_proj: tile stream; W fragments direct from global ----
  for (int jt = 0; jt < 8; ++jt) {
    const int wrow0 = jt << 6;
    const int T = (jt < 4) ? 12 : 8;
    for (int tile = w; tile < T; tile += 4) {
      const int mt = tile >> 2, nt = tile & 3;
      ffrag acc = {0.f, 0.f, 0.f, 0.f};
#pragma unroll
      for (int s8 = 0; s8 < 4; ++s8) {
        int k0 = s8 * 32 + q * 8;
        bfrag af = *(const bfrag*)&As[((mt << 4) + col) * 136 + k0];
        bfrag wf = *(const bfrag*)&w_in_b[(wrow0 + (nt << 4) + col) * 128 + k0];
        acc = __builtin_amdgcn_mfma_f32_16x16x32_bf16(wf, af, acc, 0, 0, 0);
      }
      const int chb = (nt << 4) + (q << 2);
      if (jt < 4) {
        uint2 pk = {f2bf2(acc[0], acc[1]), f2bf2(acc[2], acc[3])};
        const int ch = (jt << 6) + chb;
        if (mt < 2) {
          *(uint2*)&hx[(3 + (mt << 4) + col) * 264 + ch] = pk;
        } else if (col >= 13) {               // halo rows: positions p0-3..p0-1
          *(uint2*)&hx[(col - 13) * 264 + ch] = pk;
        }
      } else {
        uint2 pk = {f2bf2(silu_f(acc[0]), silu_f(acc[1])),
                    f2bf2(silu_f(acc[2]), silu_f(acc[3]))};
        const int m = p0 + (mt << 4) + col;
        *(uint2*)&zsb[m * 256 + ((jt - 4) << 6) + chb] = pk;
      }
    }
  }
  __syncthreads();   // hx complete; As reads done (ua overlay next)
  // ---- conv(4)+SiLU from hx (LDS) -> ua; thread = channel ----
  {
    const int k = t;
    const int lb = p0 & (L_ - 1);
    const float w0 = cw[k*4], w1 = cw[k*4+1], w2 = cw[k*4+2], w3 = cw[k*4+3];
    const float bias = cb[k];
    float x0 = (lb >= 3) ? bf2f((unsigned int)hx[0 * 264 + k]) : 0.f;
    float x1 = (lb >= 2) ? bf2f((unsigned int)hx[1 * 264 + k]) : 0.f;
    float x2 = (lb >= 1) ? bf2f((unsigned int)hx[2 * 264 + k]) : 0.f;
#pragma unroll 8
    for (int it = 0; it < 32; ++it) {
      float x3 = bf2f((unsigned int)hx[(3 + it) * 264 + k]);
      float u = silu_f(fmaf(w0, x0, fmaf(w1, x1, fmaf(w2, x2, fmaf(w3, x3, bias)))));
      ua[it * 264 + k] = f2bf(u);
      x0 = x1; x1 = x2; x2 = x3;
    }
  }
  __syncthreads();
  // ---- x_proj + dt MFMA: 36 tiles (2 pos x 18 n) over 4 waves ----
  // ntv 0,1: B/C (xw rows 8..39); ntv 2..17: dt channels via composed M.
  for (int tile = w; tile < 36; tile += 4) {
    const int mt = tile & 1, ntv = tile >> 1;
    const unsigned short* wsrc = (ntv < 2)
        ? &xw_b[(8 + (ntv << 4) + col) * 256]
        : &Mb[((((ntv - 2) << 4) + col)) * 256];
    ffrag acc = {0.f, 0.f, 0.f, 0.f};
#pragma unroll
    for (int s8 = 0; s8 < 8; ++s8) {
      int k0 = s8 * 32 + q * 8;
      bfrag af = *(const bfrag*)&ua[((mt << 4) + col) * 264 + k0];
      bfrag wf = *(const bfrag*)&wsrc[k0];
      acc = __builtin_amdgcn_mfma_f32_16x16x32_bf16(wf, af, acc, 0, 0, 0);
    }
    const int pos = (mt << 4) + col;
    const int m = p0 + pos;
    if (ntv < 2) {
      const int n0 = (ntv << 4) + (q << 2);
      float4 v = {acc[0], acc[1], acc[2], acc[3]};
      if (n0 < 16) {
        *(float4*)&Bb[m * 16 + n0] = v;
        *(float4*)&Bs_l[pos * 16 + n0] = v;
      } else {
        *(float4*)&Cb[m * 16 + (n0 - 16)] = v;
      }
    } else {
      const int ch = ((ntv - 2) << 4) + (q << 2);
      float4 bia = *(const float4*)&dtpb[ch];
      float d0 = softplus_f(acc[0] + bia.x);
      float d1 = softplus_f(acc[1] + bia.y);
      float d2 = softplus_f(acc[2] + bia.z);
      float d3 = softplus_f(acc[3] + bia.w);
      unsigned long long uq4 = *(const unsigned long long*)&ua[pos * 264 + ch];
      uint4 pk;
      pk.x = (unsigned int)(unsigned short)(uq4)       | ((unsigned int)f2bf(d0) << 16);
      pk.y = (unsigned int)(unsigned short)(uq4 >> 16) | ((unsigned int)f2bf(d1) << 16);
      pk.z = (unsigned int)(unsigned short)(uq4 >> 32) | ((unsigned int)f2bf(d2) << 16);
      pk.w = (unsigned int)(unsigned short)(uq4 >> 48) | ((unsigned int)f2bf(d3) << 16);
      *(uint4*)&udt[m * 256 + ch] = pk;
    }
  }
  __syncthreads();   // udt writes drained (vmcnt(0)+barrier) before read-back
  // ---- inline scan phase 1 (thread = channel; udt prefetch depth 2) ----
  {
    const int d = t;
    const int bb = p0 >> 12;
    const int cc = (p0 & (L_ - 1)) >> 5;
    const int bc = bb * NC + cc;
    float a[16];
    bool okl = true;
#pragma unroll
    for (int j = 0; j < 16; ++j) {
      a[j] = -__expf(alog[d * 16 + j]);
      float tgt = (float)(j + 1);
      okl = okl && (fabsf(a[j] + tgt) <= 1e-3f * tgt);
    }
    const bool fast = (bool)__all((int)okl);
    f32x2 h2[8] = {{0.f,0.f},{0.f,0.f},{0.f,0.f},{0.f,0.f},
                   {0.f,0.f},{0.f,0.f},{0.f,0.f},{0.f,0.f}};
    float sdt = 0.f;
    unsigned int wv0 = udt[(p0 + 0) * 256 + d];
    unsigned int wv1 = udt[(p0 + 1) * 256 + d];
#pragma unroll 2
    for (int pp = 0; pp < 32; ++pp) {
      const int p2 = (pp + 2 < 32) ? pp + 2 : 31;
      unsigned int wv2 = udt[(p0 + p2) * 256 + d];
      float uv  = bf2f(wv0 & 0xFFFFu);
      float dtv = bf2f(wv0 >> 16);
      float du = dtv * uv;
      sdt += dtv;
      const float* brow = &Bs_l[pp * 16];
      float4 b0 = *(const float4*)&brow[0];
      float4 b1 = *(const float4*)&brow[4];
      float4 b2 = *(const float4*)&brow[8];
      float4 b3 = *(const float4*)&brow[12];
      f32x2 B2[8] = {{b0.x,b0.y},{b0.z,b0.w},{b1.x,b1.y},{b1.z,b1.w},
                     {b2.x,b2.y},{b2.z,b2.w},{b3.x,b3.y},{b3.z,b3.w}};
      f32x2 du2 = {du, du};
      if (fast) {
        float e1 = __expf(-dtv);
        float e2 = e1 * e1;
        f32x2 dA = {e1, e2};
        f32x2 e22 = {e2, e2};
#pragma unroll
        for (int jj = 0; jj < 8; ++jj) {
          h2[jj] = dA * h2[jj] + du2 * B2[jj];
          dA = dA * e22;
        }
      } else {
#pragma unroll
        for (int j = 0; j < 16; ++j) {
          float dA = __expf(dtv * a[j]);
          h2[j >> 1][j & 1] = fmaf(dA, h2[j >> 1][j & 1], du * B2[j >> 1][j & 1]);
        }
      }
      wv0 = wv1; wv1 = wv2;
    }
#pragma unroll
    for (int j = 0; j < 16; ++j) {
      int o = (bc * 16 + j) * 256 + d;
      cP[o]  = f2bf(__expf(a[j] * sdt));
      cHe[o] = f2bf(h2[j >> 1][j & 1]);
    }
  }
}

// ---------------------------------------------------------------------------
// Hierarchical combine (NC=128, bf16): 512 thr = 64 sd x 8 segments of 16.
// ---------------------------------------------------------------------------
__global__ __launch_bounds__(512)
void scan_combine(unsigned short* __restrict__ cP, const unsigned short* __restrict__ cHe) {
  __shared__ float segP[64 * 9], segH[64 * 9], segS[64 * 9];
  const int t = threadIdx.x;
  const int sdl = t & 63, seg = t >> 6;
  const int blk = blockIdx.x;
  const int b = blk >> 6, grp = blk & 63;
  const int sd = (grp << 6) + sdl;
  const int base = b * NC * 4096 + sd;
  float Pacc = 1.f, Hacc = 0.f;
#pragma unroll
  for (int i = 0; i < 16; ++i) {
    int idx = base + (seg * 16 + i) * 4096;
    float p = bf2f((unsigned int)cP[idx]);
    float he = bf2f((unsigned int)cHe[idx]);
    Hacc = fmaf(p, Hacc, he);
    Pacc *= p;
  }
  segP[sdl * 9 + seg] = Pacc;
  segH[sdl * 9 + seg] = Hacc;
  __syncthreads();
  if (t < 64) {
    float hs = 0.f;
#pragma unroll
    for (int s2 = 0; s2 < 8; ++s2) {
      segS[t * 9 + s2] = hs;
      hs = fmaf(segP[t * 9 + s2], hs, segH[t * 9 + s2]);
    }
  }
  __syncthreads();
  float hs = segS[sdl * 9 + seg];
#pragma unroll
  for (int i = 0; i < 16; ++i) {
    int idx = base + (seg * 16 + i) * 4096;
    float p = bf2f((unsigned int)cP[idx]);
    float he = bf2f((unsigned int)cHe[idx]);
    cP[idx] = f2bf(hs);
    hs = fmaf(p, hs, he);
  }
}

// ---------------------------------------------------------------------------
// FUSED scan phase 3 + out_proj + LayerNorm + fc + ReLU (unchanged r10).
// ---------------------------------------------------------------------------
__global__ __launch_bounds__(512, 4)
void scan3_out_ln_fc(const unsigned int* __restrict__ udt,
                     const float* __restrict__ Bb, const float* __restrict__ Cb,
                     const float* __restrict__ alog, const unsigned short* __restrict__ hst,
                     const float* __restrict__ dsk,
                     const unsigned short* __restrict__ zsb,
                     const unsigned short* __restrict__ ow_b,
                     const float* __restrict__ gamma, const float* __restrict__ beta,
                     const unsigned short* __restrict__ fcw_b, float* __restrict__ out) {
  __shared__ float Bs[CH2 * 16];             // 4 KB
  __shared__ float Cs[CH2 * 16];             // 4 KB
  __shared__ unsigned short smA[64 * 264];   // ya (stride 264); later hnb (stride 136)
  __shared__ unsigned short smB[128 * 136];  // ow half (stride 264); later fcw (136)
  __shared__ float pS1[128], pS2[128];       // LN cross-wave partials [np*64+row]
  const int bc = blockIdx.x;
  const int b = bc >> 6, cc = bc & 63;
  const int t = threadIdx.x;
  const int l = t & 63, w = t >> 6;
  const int chh = t >> 8;                     // which of the 2 parallel chunks
  const int d = t & 255;                      // channel
  const int base = b * L_ + (cc << 1) * CH;   // 64-position tile start
  const int cbase = base + chh * CH;          // this chunk's start
  const int hc = b * NC + (cc << 1) + chh;    // h_start chunk index
  if (t < CH2 * 4)           ((float4*)Bs)[t]            = *(const float4*)&Bb[base * 16 + (t << 2)];
  else if (t < CH2 * 8)      ((float4*)Cs)[t - CH2 * 4]  = *(const float4*)&Cb[base * 16 + ((t - CH2 * 4) << 2)];
  float a[16];
  bool okl = true;
#pragma unroll
  for (int j = 0; j < 16; ++j) {
    a[j] = -__expf(alog[d * 16 + j]);
    float tgt = (float)(j + 1);
    okl = okl && (fabsf(a[j] + tgt) <= 1e-3f * tgt);
  }
  const bool fast = (bool)__all((int)okl);
  const float dskv = dsk[d];
  f32x2 h2[8];
#pragma unroll
  for (int jj = 0; jj < 8; ++jj) {
    h2[jj][0] = bf2f((unsigned int)hst[(hc * 16 + (jj << 1)) * 256 + d]);
    h2[jj][1] = bf2f((unsigned int)hst[(hc * 16 + (jj << 1) + 1) * 256 + d]);
  }
  unsigned int wv0 = udt[cbase * 256 + d];
  unsigned int wv1 = udt[(cbase + 1) * 256 + d];
  unsigned short zv0 = zsb[cbase * 256 + d];
  unsigned short zv1 = zsb[(cbase + 1) * 256 + d];
  __syncthreads();
#pragma unroll 2
  for (int ll = 0; ll < CH; ++ll) {
    const int l2 = (ll + 2 < CH) ? ll + 2 : CH - 1;
    unsigned int wv2 = udt[(cbase + l2) * 256 + d];
    unsigned short zv2 = zsb[(cbase + l2) * 256 + d];
    const float* brow = &Bs[(chh * CH + ll) * 16];
    const float* crow = &Cs[(chh * CH + ll) * 16];
    float4 b0 = *(const float4*)&brow[0];
    float4 b1 = *(const float4*)&brow[4];
    float4 b2 = *(const float4*)&brow[8];
    float4 b3 = *(const float4*)&brow[12];
    float4 c0 = *(const float4*)&crow[0];
    float4 c1 = *(const float4*)&crow[4];
    float4 c2 = *(const float4*)&crow[8];
    float4 c3 = *(const float4*)&crow[12];
    float uv  = bf2f(wv0 & 0xFFFFu);
    float dtv = bf2f(wv0 >> 16);
    f32x2 B2[8] = {{b0.x,b0.y},{b0.z,b0.w},{b1.x,b1.y},{b1.z,b1.w},
                   {b2.x,b2.y},{b2.z,b2.w},{b3.x,b3.y},{b3.z,b3.w}};
    f32x2 C2[8] = {{c0.x,c0.y},{c0.z,c0.w},{c1.x,c1.y},{c1.z,c1.w},
                   {c2.x,c2.y},{c2.z,c2.w},{c3.x,c3.y},{c3.z,c3.w}};
    float du = dtv * uv;
    f32x2 du2 = {du, du};
    f32x2 y2 = {0.f, 0.f};
    if (fast) {
      float e1 = __expf(-dtv);
      float e2 = e1 * e1;
      f32x2 dA = {e1, e2};
      f32x2 e22 = {e2, e2};
#pragma unroll
      for (int jj = 0; jj < 8; ++jj) {
        h2[jj] = dA * h2[jj] + du2 * B2[jj];
        y2 = y2 + h2[jj] * C2[jj];
        dA = dA * e22;
      }
    } else {
#pragma unroll
      for (int j = 0; j < 16; ++j) {
        float dA = __expf(dtv * a[j]);
        float hh = fmaf(dA, h2[j >> 1][j & 1], du * B2[j >> 1][j & 1]);
        h2[j >> 1][j & 1] = hh;
        y2[j & 1] = fmaf(hh, C2[j >> 1][j & 1], y2[j & 1]);
      }
    }
    float y = y2.x + y2.y;
    float zs = bf2f((unsigned int)zv0);
    smA[(chh * CH + ll) * 264 + d] = f2bf(fmaf(uv, dskv, y) * zs);   // ya, bf16
    wv0 = wv1; wv1 = wv2; zv0 = zv1; zv1 = zv2;
  }
  // -------- epilogue (ALL 8 waves): out_proj -> LN -> fc -> ReLU --------
  const int q = l >> 4, col = l & 15;
  const int rw = w & 3, np = w >> 2;          // row-group x channel-half
  ffrag acc[2][2];
  for (int nt2 = 0; nt2 < 2; ++nt2) {
    __syncthreads();           // iter0: ya complete; iter1: prior smB reads done
    for (int i = t; i < 64 * 32; i += 512) {
      int row = i >> 5, c8 = (i & 31) << 3;
      *(uint4*)&smB[row * 264 + c8] = *(const uint4*)&ow_b[((nt2 << 6) + row) * 256 + c8];
    }
    __syncthreads();
#pragma unroll
    for (int nt = 0; nt < 2; ++nt) acc[nt2][nt] = (ffrag){0.f, 0.f, 0.f, 0.f};
#pragma unroll
    for (int s8 = 0; s8 < 8; ++s8) {
      int k0 = s8 * 32 + q * 8;
      bfrag af = *(const bfrag*)&smA[((rw << 4) + col) * 264 + k0];
#pragma unroll
      for (int nt = 0; nt < 2; ++nt) {
        bfrag bf_ = *(const bfrag*)&smB[((((np << 1) + nt) << 4) + col) * 264 + k0];
        acc[nt2][nt] = __builtin_amdgcn_mfma_f32_16x16x32_bf16(af, bf_, acc[nt2][nt], 0, 0, 0);
      }
    }
  }
  float s1v[4], s2v[4];
#pragma unroll
  for (int i = 0; i < 4; ++i) {
    float s1 = 0.f, s2 = 0.f;
#pragma unroll
    for (int nt2 = 0; nt2 < 2; ++nt2)
#pragma unroll
      for (int nt = 0; nt < 2; ++nt) {
        float v = acc[nt2][nt][i];
        s1 += v; s2 = fmaf(v, v, s2);
      }
    s1 += __shfl_xor(s1, 1); s2 += __shfl_xor(s2, 1);
    s1 += __shfl_xor(s1, 2); s2 += __shfl_xor(s2, 2);
    s1 += __shfl_xor(s1, 4); s2 += __shfl_xor(s2, 4);
    s1 += __shfl_xor(s1, 8); s2 += __shfl_xor(s2, 8);
    s1v[i] = s1; s2v[i] = s2;
  }
  if (col == 0) {
#pragma unroll
    for (int i = 0; i < 4; ++i) {
      int r = (rw << 4) + (q << 2) + i;
      pS1[(np << 6) + r] = s1v[i];
      pS2[(np << 6) + r] = s2v[i];
    }
  }
  __syncthreads();   // partials ready; all smA(ya)/smB(ow) reads done
  float mu[4], rs[4];
#pragma unroll
  for (int i = 0; i < 4; ++i) {
    int r = (rw << 4) + (q << 2) + i;
    float s1 = pS1[r] + pS1[64 + r];
    float s2 = pS2[r] + pS2[64 + r];
    mu[i] = s1 * (1.f / DM);
    float var = s2 * (1.f / DM) - mu[i] * mu[i];
    rs[i] = rsqrtf(var + 1e-5f);
  }
#pragma unroll
  for (int nt2 = 0; nt2 < 2; ++nt2)
#pragma unroll
    for (int nt = 0; nt < 2; ++nt) {
      int n = (nt2 << 6) + ((((np << 1) + nt)) << 4) + col;
      float g = gamma[n], be = beta[n];
#pragma unroll
      for (int i = 0; i < 4; ++i) {
        int r = (rw << 4) + (q << 2) + i;
        smA[r * 136 + n] = f2bf(fmaf((acc[nt2][nt][i] - mu[i]) * rs[i], g, be));
      }
    }
  for (int i = t; i < 128 * 16; i += 512) {
    int row = i >> 4, c8 = (i & 15) << 3;
    *(uint4*)&smB[row * 136 + c8] = *(const uint4*)&fcw_b[row * 128 + c8];
  }
  __syncthreads();
  ffrag a2[4] = {{0.f,0.f,0.f,0.f},{0.f,0.f,0.f,0.f},{0.f,0.f,0.f,0.f},{0.f,0.f,0.f,0.f}};
#pragma unroll
  for (int s8 = 0; s8 < 4; ++s8) {
    int k0 = s8 * 32 + q * 8;
    bfrag af = *(const bfrag*)&smA[((rw << 4) + col) * 136 + k0];
#pragma unroll
    for (int nt = 0; nt < 4; ++nt) {
      bfrag bf_ = *(const bfrag*)&smB[((((np << 2) + nt) << 4) + col) * 136 + k0];
      a2[nt] = __builtin_amdgcn_mfma_f32_16x16x32_bf16(af, bf_, a2[nt], 0, 0, 0);
    }
  }
#pragma unroll
  for (int nt = 0; nt < 4; ++nt)
#pragma unroll
    for (int i = 0; i < 4; ++i) {
      int ml = (rw << 4) + (q << 2) + i;
      out[(base + ml) * 128 + (((np << 2) + nt) << 4) + col] = fmaxf(a2[nt][i], 0.f);
    }
}

extern "C" void kernel_launch(void* const* d_in, const int* in_sizes, int n_in,
                              void* d_out, int out_size, void* d_ws, size_t ws_size,
                              hipStream_t stream) {
  (void)in_sizes; (void)n_in; (void)out_size; (void)ws_size;
  const float* s    = (const float*)d_in[0];
  const float* w_in = (const float*)d_in[1];
  const float* cw   = (const float*)d_in[2];
  const float* cb   = (const float*)d_in[3];
  const float* xw   = (const float*)d_in[4];
  const float* dtw  = (const float*)d_in[5];
  const float* dtpb = (const float*)d_in[6];
  const float* alog = (const float*)d_in[7];
  const float* dsk  = (const float*)d_in[8];
  const float* ow   = (const float*)d_in[9];
  const float* gam  = (const float*)d_in[10];
  const float* bet  = (const float*)d_in[11];
  const float* fcw  = (const float*)d_in[12];
  float* out = (float*)d_out;
  float* ws  = (float*)d_ws;

  // float-unit offsets; all regions disjoint (re-audited r11; bf16 regions
  // sized as (num bf16 values)/2 floats):
  unsigned short* zsb  = (unsigned short*)(ws + 4194304);     // [4194304, 8388608)
  unsigned int*   udt  = (unsigned int*)(ws + 8388608);       // [8388608, 16777216)
  float*          Bb   = ws + 16777216;                       // [16777216, 17301504)
  float*          Cb   = ws + 17301504;                       // [17301504, 17825792)
  unsigned short* cP   = (unsigned short*)(ws + 17825792);    // [17825792, 19922944)
  unsigned short* cHe  = (unsigned short*)(ws + 19922944);    // [19922944, 22020096)
  unsigned short* w_in_b = (unsigned short*)(ws + 22020096);  // 65536 bf16 -> [22020096, 22052864)
  unsigned short* xw_b   = (unsigned short*)(ws + 22052864);  // 10240 bf16 -> [22052864, 22057984)
  unsigned short* ow_b   = (unsigned short*)(ws + 22057984);  // 32768 bf16 -> [22057984, 22074368)
  unsigned short* fcw_b  = (unsigned short*)(ws + 22074368);  // 16384 bf16 -> [22074368, 22082560)
  unsigned short* Mb     = (unsigned short*)(ws + 22082560);  // 65536 bf16 -> [22082560, 22115328)

  // 0. one-shot weight f32->bf16 + composed dt matrix M = dtw x xw[0:8]
  prep_weights<<<186, 256, 0, stream>>>(w_in, xw, ow, fcw, dtw,
                                        w_in_b, xw_b, ow_b, fcw_b, Mb);
  // 1. MEGA-FUSED front end: in_proj + conv + x_proj/dt-MFMA + scan phase 1
  xproj_dtproj<<<M_ / CH, 256, 0, stream>>>(s, w_in_b, xw_b, Mb, dtpb, cw, cb, alog,
                                            Bb, Cb, udt, zsb, cP, cHe);
  // 2. inter-chunk combine
  scan_combine<<<512, 512, 0, stream>>>(cP, cHe);
  // 3. FUSED scan phase 3 + out_proj + LN + fc + ReLU (8-wave epilogue)
  scan3_out_ln_fc<<<B_ * NC / 2, 512, 0, stream>>>(udt, Bb, Cb, alog, cP, dsk, zsb,
                                                   ow_b, gam, bet, fcw_b, out);
}

// Round 12
// 170.212 us; speedup vs baseline: 1.1193x; 1.1193x over previous
//
#include <hip/hip_runtime.h>
#include <math.h>

#define B_ 8
#define L_ 4096
#define DM 128
#define DI 256
#define DSN 16
#define RK 8
#define M_ (B_*L_)      // 32768 positions
#define NC 128          // number of scan chunks
#define CH 32           // chunk length (NC*CH == L_)
#define CH2 64          // fused phase3 tile: 2 chunks

typedef __attribute__((ext_vector_type(8))) short bfrag;   // 8 bf16 (4 VGPRs)
typedef __attribute__((ext_vector_type(4))) float ffrag;   // 4 fp32 acc
typedef __attribute__((ext_vector_type(2))) float f32x2;   // packed-math pair

__device__ __forceinline__ float silu_f(float x) {
  return x * __builtin_amdgcn_rcpf(1.f + __expf(-x));
}
__device__ __forceinline__ float softplus_f(float x) {
  return (x > 20.f) ? x : __logf(1.f + __expf(x));
}

__device__ __forceinline__ unsigned short f2bf(float f) {
  unsigned int u = __builtin_bit_cast(unsigned int, f);
  unsigned int r = (u + 0x7FFFu + ((u >> 16) & 1u)) >> 16;   // RNE
  return (unsigned short)r;
}
__device__ __forceinline__ unsigned int f2bf2(float lo, float hi) {
  return (unsigned int)f2bf(lo) | ((unsigned int)f2bf(hi) << 16);
}
__device__ __forceinline__ float bf2f(unsigned int us) {
  return __builtin_bit_cast(float, us << 16);
}

// ---------------------------------------------------------------------------
// One-shot weight prep: f32 -> bf16 (same RNE -> bit-identical results).
// ---------------------------------------------------------------------------
__global__ __launch_bounds__(256)
void prep_weights(const float* __restrict__ w_in, const float* __restrict__ xw,
                  const float* __restrict__ ow, const float* __restrict__ fcw,
                  unsigned short* __restrict__ w_in_b, unsigned short* __restrict__ xw_b,
                  unsigned short* __restrict__ ow_b, unsigned short* __restrict__ fcw_b) {
  const int i = blockIdx.x * 256 + threadIdx.x;
  const float* src; unsigned short* dst; int j;
  if (i < 16384)      { src = w_in; dst = w_in_b; j = i; }           // 512x128
  else if (i < 18944) { src = xw;   dst = xw_b;   j = i - 16384; }   // 40x256
  else if (i < 27136) { src = ow;   dst = ow_b;   j = i - 18944; }   // 128x256
  else if (i < 31232) { src = fcw;  dst = fcw_b;  j = i - 27136; }   // 128x128
  else return;
  float4 v = *(const float4*)&src[j << 2];
  uint2 p = {f2bf2(v.x, v.y), f2bf2(v.z, v.w)};
  *(uint2*)&dst[j << 2] = p;
}

// ---------------------------------------------------------------------------
// MEGA-FUSED front end (r9/r10 structure — best measured): 1024 blocks x 256
// threads, 1 scan chunk per block, 4 blocks/CU. Weights direct from global.
// ---------------------------------------------------------------------------
__global__ __launch_bounds__(256, 4)
void xproj_dtproj(const float* __restrict__ s, const unsigned short* __restrict__ w_in_b,
                  const unsigned short* __restrict__ xw_b,
                  const float* __restrict__ dtw, const float* __restrict__ dtpb,
                  const float* __restrict__ cw, const float* __restrict__ cb,
                  const float* __restrict__ alog,
                  float* __restrict__ Bb, float* __restrict__ Cb,
                  unsigned int* __restrict__ udt,
                  unsigned short* __restrict__ zsb,
                  unsigned short* __restrict__ cP, unsigned short* __restrict__ cHe) {
  __shared__ __align__(16) char pool[38960];
  unsigned short* As = (unsigned short*)pool;              // 48*136*2 = 13056
  unsigned short* ua = (unsigned short*)pool;              // 32*264*2 = 16896 (overlay As)
  unsigned short* hx = (unsigned short*)(pool + 16896);    // 35*264*2 = 18480
  float* dtr_s = (float*)(pool + 35376);                   // 32*12*4  = 1536
  float* Bs_l  = (float*)(pool + 36912);                   // 32*16*4  = 2048
  const int t = threadIdx.x;
  const int p0 = blockIdx.x << 5;             // 32-position tile = one chunk
  const int w = t >> 6, l = t & 63, q = l >> 4, col = l & 15;

  // ---- stage A (32 main rows + 16 halo rows of s, f32 -> bf16) ----
  for (int i = t; i < 48 * 32; i += 256) {
    int row = i >> 5, c4 = i & 31;
    int pos = (row < 32) ? (p0 + row) : (p0 - 16 + (row - 32));
    if (pos < 0) pos = 0;                     // block 0 halo: clamped, masked later
    float4 av = *(const float4*)&s[pos * 128 + (c4 << 2)];
    uint2 ap = {f2bf2(av.x, av.y), f2bf2(av.z, av.w)};
    *(uint2*)&As[row * 136 + (c4 << 2)] = ap;
  }
  __syncthreads();
  // ---- in_proj: tile stream; W fragments direct from global ----
  for (int jt = 0; jt < 8; ++jt) {
    const int wrow0 = jt << 6;
    const int T = (jt < 4) ? 12 : 8;
    for (int tile = w; tile < T; tile += 4) {
      const int mt = tile >> 2, nt = tile & 3;
      ffrag acc = {0.f, 0.f, 0.f, 0.f};
#pragma unroll
      for (int s8 = 0; s8 < 4; ++s8) {
        int k0 = s8 * 32 + q * 8;
        bfrag af = *(const bfrag*)&As[((mt << 4) + col) * 136 + k0];
        bfrag wf = *(const bfrag*)&w_in_b[(wrow0 + (nt << 4) + col) * 128 + k0];
        acc = __builtin_amdgcn_mfma_f32_16x16x32_bf16(wf, af, acc, 0, 0, 0);
      }
      const int chb = (nt << 4) + (q << 2);
      if (jt < 4) {
        uint2 pk = {f2bf2(acc[0], acc[1]), f2bf2(acc[2], acc[3])};
        const int ch = (jt << 6) + chb;
        if (mt < 2) {
          *(uint2*)&hx[(3 + (mt << 4) + col) * 264 + ch] = pk;
        } else if (col >= 13) {               // halo rows: positions p0-3..p0-1
          *(uint2*)&hx[(col - 13) * 264 + ch] = pk;
        }
      } else {
        uint2 pk = {f2bf2(silu_f(acc[0]), silu_f(acc[1])),
                    f2bf2(silu_f(acc[2]), silu_f(acc[3]))};
        const int m = p0 + (mt << 4) + col;
        *(uint2*)&zsb[m * 256 + ((jt - 4) << 6) + chb] = pk;
      }
    }
  }
  __syncthreads();   // hx complete; As reads done (ua overlay next)
  // ---- conv(4)+SiLU from hx (LDS) -> ua; thread = channel ----
  {
    const int k = t;
    const int lb = p0 & (L_ - 1);
    const float w0 = cw[k*4], w1 = cw[k*4+1], w2 = cw[k*4+2], w3 = cw[k*4+3];
    const float bias = cb[k];
    float x0 = (lb >= 3) ? bf2f((unsigned int)hx[0 * 264 + k]) : 0.f;
    float x1 = (lb >= 2) ? bf2f((unsigned int)hx[1 * 264 + k]) : 0.f;
    float x2 = (lb >= 1) ? bf2f((unsigned int)hx[2 * 264 + k]) : 0.f;
#pragma unroll 8
    for (int it = 0; it < 32; ++it) {
      float x3 = bf2f((unsigned int)hx[(3 + it) * 264 + k]);
      float u = silu_f(fmaf(w0, x0, fmaf(w1, x1, fmaf(w2, x2, fmaf(w3, x3, bias)))));
      ua[it * 264 + k] = f2bf(u);
      x0 = x1; x1 = x2; x2 = x3;
    }
  }
  __syncthreads();
  // ---- x_proj MFMA: 6 tiles (2 m x 3 n) over 4 waves; xw direct ----
  for (int tile = w; tile < 6; tile += 4) {
    const int mt = tile & 1, nt = tile >> 1;
    ffrag acc = {0.f, 0.f, 0.f, 0.f};
#pragma unroll
    for (int s8 = 0; s8 < 8; ++s8) {
      int k0 = s8 * 32 + q * 8;
      bfrag af = *(const bfrag*)&ua[((mt << 4) + col) * 264 + k0];
      const int nrow = (nt << 4) + col;
      bfrag wf = {0, 0, 0, 0, 0, 0, 0, 0};
      if (nrow < 40) wf = *(const bfrag*)&xw_b[nrow * 256 + k0];
      acc = __builtin_amdgcn_mfma_f32_16x16x32_bf16(wf, af, acc, 0, 0, 0);
    }
    const int ml = (mt << 4) + col;
    const int m = p0 + ml;
    const int n0 = (nt << 4) + (q << 2);
    float4 v = {acc[0], acc[1], acc[2], acc[3]};
    if (n0 < 8) {
      *(float4*)&dtr_s[ml * 12 + n0] = v;
    } else if (n0 < 24) {
      *(float4*)&Bb[m * 16 + (n0 - 8)] = v;
      *(float4*)&Bs_l[ml * 16 + (n0 - 8)] = v;
    } else if (n0 < 40) {
      *(float4*)&Cb[m * 16 + (n0 - 24)] = v;
    }                                         // n0 >= 40: zero rows, drop
  }
  __syncthreads();
  // ---- dt_proj + softplus + inline scan phase 1 (thread = channel) ----
  {
    const int d = t;
    const int bb = p0 >> 12;
    const int cc = (p0 & (L_ - 1)) >> 5;
    const int bc = bb * NC + cc;
    float w8[8];
    *(float4*)&w8[0] = *(const float4*)&dtw[d * 8];
    *(float4*)&w8[4] = *(const float4*)&dtw[d * 8 + 4];
    const float bias = dtpb[d];
    float a[16];
    bool okl = true;
#pragma unroll
    for (int j = 0; j < 16; ++j) {
      a[j] = -__expf(alog[d * 16 + j]);
      float tgt = (float)(j + 1);
      okl = okl && (fabsf(a[j] + tgt) <= 1e-3f * tgt);
    }
    const bool fast = (bool)__all((int)okl);
    f32x2 h2[8] = {{0.f,0.f},{0.f,0.f},{0.f,0.f},{0.f,0.f},
                   {0.f,0.f},{0.f,0.f},{0.f,0.f},{0.f,0.f}};
    float sdt = 0.f;
#pragma unroll 2
    for (int pp = 0; pp < 32; ++pp) {
      float r0[8];
      *(float4*)&r0[0] = *(const float4*)&dtr_s[pp * 12];
      *(float4*)&r0[4] = *(const float4*)&dtr_s[pp * 12 + 4];
      float a2 = bias;
#pragma unroll
      for (int r2 = 0; r2 < 8; ++r2) a2 = fmaf(r0[r2], w8[r2], a2);
      float sp = softplus_f(a2);
      unsigned int uq = (unsigned int)ua[pp * 264 + d];
      unsigned short spb = f2bf(sp);
      udt[(p0 + pp) * 256 + d] = uq | ((unsigned int)spb << 16);
      float dtv = bf2f((unsigned int)spb);
      float uv  = bf2f(uq);
      float du = dtv * uv;
      sdt += dtv;
      const float* brow = &Bs_l[pp * 16];
      float4 b0 = *(const float4*)&brow[0];
      float4 b1 = *(const float4*)&brow[4];
      float4 b2 = *(const float4*)&brow[8];
      float4 b3 = *(const float4*)&brow[12];
      f32x2 B2[8] = {{b0.x,b0.y},{b0.z,b0.w},{b1.x,b1.y},{b1.z,b1.w},
                     {b2.x,b2.y},{b2.z,b2.w},{b3.x,b3.y},{b3.z,b3.w}};
      f32x2 du2 = {du, du};
      if (fast) {
        float e1 = __expf(-dtv);
        float e2 = e1 * e1;
        f32x2 dA = {e1, e2};
        f32x2 e22 = {e2, e2};
#pragma unroll
        for (int jj = 0; jj < 8; ++jj) {
          h2[jj] = dA * h2[jj] + du2 * B2[jj];
          dA = dA * e22;
        }
      } else {
#pragma unroll
        for (int j = 0; j < 16; ++j) {
          float dA = __expf(dtv * a[j]);
          h2[j >> 1][j & 1] = fmaf(dA, h2[j >> 1][j & 1], du * B2[j >> 1][j & 1]);
        }
      }
    }
#pragma unroll
    for (int j = 0; j < 16; ++j) {
      int o = (bc * 16 + j) * 256 + d;
      cP[o]  = f2bf(__expf(a[j] * sdt));
      cHe[o] = f2bf(h2[j >> 1][j & 1]);
    }
  }
}

// ---------------------------------------------------------------------------
// Hierarchical combine (NC=128, bf16): 512 thr = 64 sd x 8 segments of 16.
// ---------------------------------------------------------------------------
__global__ __launch_bounds__(512)
void scan_combine(unsigned short* __restrict__ cP, const unsigned short* __restrict__ cHe) {
  __shared__ float segP[64 * 9], segH[64 * 9], segS[64 * 9];
  const int t = threadIdx.x;
  const int sdl = t & 63, seg = t >> 6;
  const int blk = blockIdx.x;
  const int b = blk >> 6, grp = blk & 63;
  const int sd = (grp << 6) + sdl;
  const int base = b * NC * 4096 + sd;
  float Pacc = 1.f, Hacc = 0.f;
#pragma unroll
  for (int i = 0; i < 16; ++i) {
    int idx = base + (seg * 16 + i) * 4096;
    float p = bf2f((unsigned int)cP[idx]);
    float he = bf2f((unsigned int)cHe[idx]);
    Hacc = fmaf(p, Hacc, he);
    Pacc *= p;
  }
  segP[sdl * 9 + seg] = Pacc;
  segH[sdl * 9 + seg] = Hacc;
  __syncthreads();
  if (t < 64) {
    float hs = 0.f;
#pragma unroll
    for (int s2 = 0; s2 < 8; ++s2) {
      segS[t * 9 + s2] = hs;
      hs = fmaf(segP[t * 9 + s2], hs, segH[t * 9 + s2]);
    }
  }
  __syncthreads();
  float hs = segS[sdl * 9 + seg];
#pragma unroll
  for (int i = 0; i < 16; ++i) {
    int idx = base + (seg * 16 + i) * 4096;
    float p = bf2f((unsigned int)cP[idx]);
    float he = bf2f((unsigned int)cHe[idx]);
    cP[idx] = f2bf(hs);
    hs = fmaf(p, hs, he);
  }
}

// ---------------------------------------------------------------------------
// FUSED scan phase 3 + out_proj + LayerNorm + fc + ReLU (r10 structure).
// r12: udt/zsb prefetch deepened 2 -> 4 (rolling 4-slot register buffer,
// unroll 4 so all slot indices are compile-time). udt is 32 MB (> L2) so
// these are HBM reads; depth-4 roughly doubles issue-to-use distance.
// ---------------------------------------------------------------------------
__global__ __launch_bounds__(512, 4)
void scan3_out_ln_fc(const unsigned int* __restrict__ udt,
                     const float* __restrict__ Bb, const float* __restrict__ Cb,
                     const float* __restrict__ alog, const unsigned short* __restrict__ hst,
                     const float* __restrict__ dsk,
                     const unsigned short* __restrict__ zsb,
                     const unsigned short* __restrict__ ow_b,
                     const float* __restrict__ gamma, const float* __restrict__ beta,
                     const unsigned short* __restrict__ fcw_b, float* __restrict__ out) {
  __shared__ float Bs[CH2 * 16];             // 4 KB
  __shared__ float Cs[CH2 * 16];             // 4 KB
  __shared__ unsigned short smA[64 * 264];   // ya (stride 264); later hnb (stride 136)
  __shared__ unsigned short smB[128 * 136];  // ow half (stride 264); later fcw (136)
  __shared__ float pS1[128], pS2[128];       // LN cross-wave partials [np*64+row]
  const int bc = blockIdx.x;
  const int b = bc >> 6, cc = bc & 63;
  const int t = threadIdx.x;
  const int l = t & 63, w = t >> 6;
  const int chh = t >> 8;                     // which of the 2 parallel chunks
  const int d = t & 255;                      // channel
  const int base = b * L_ + (cc << 1) * CH;   // 64-position tile start
  const int cbase = base + chh * CH;          // this chunk's start
  const int hc = b * NC + (cc << 1) + chh;    // h_start chunk index
  if (t < CH2 * 4)           ((float4*)Bs)[t]            = *(const float4*)&Bb[base * 16 + (t << 2)];
  else if (t < CH2 * 8)      ((float4*)Cs)[t - CH2 * 4]  = *(const float4*)&Cb[base * 16 + ((t - CH2 * 4) << 2)];
  float a[16];
  bool okl = true;
#pragma unroll
  for (int j = 0; j < 16; ++j) {
    a[j] = -__expf(alog[d * 16 + j]);
    float tgt = (float)(j + 1);
    okl = okl && (fabsf(a[j] + tgt) <= 1e-3f * tgt);
  }
  const bool fast = (bool)__all((int)okl);
  const float dskv = dsk[d];
  f32x2 h2[8];
#pragma unroll
  for (int jj = 0; jj < 8; ++jj) {
    h2[jj][0] = bf2f((unsigned int)hst[(hc * 16 + (jj << 1)) * 256 + d]);
    h2[jj][1] = bf2f((unsigned int)hst[(hc * 16 + (jj << 1) + 1) * 256 + d]);
  }
  // depth-4 rolling prefetch of udt/zsb
  unsigned int wvq[4];
  unsigned short zvq[4];
#pragma unroll
  for (int k = 0; k < 4; ++k) {
    int ik = (k < CH) ? k : CH - 1;
    wvq[k] = udt[(cbase + ik) * 256 + d];
    zvq[k] = zsb[(cbase + ik) * 256 + d];
  }
  __syncthreads();
#pragma unroll 4
  for (int ll = 0; ll < CH; ++ll) {
    const int sl = ll & 3;                    // compile-time under unroll 4
    const unsigned int wv0 = wvq[sl];
    const unsigned short zv0 = zvq[sl];
    const int l4 = (ll + 4 < CH) ? ll + 4 : CH - 1;
    wvq[sl] = udt[(cbase + l4) * 256 + d];
    zvq[sl] = zsb[(cbase + l4) * 256 + d];
    const float* brow = &Bs[(chh * CH + ll) * 16];
    const float* crow = &Cs[(chh * CH + ll) * 16];
    float4 b0 = *(const float4*)&brow[0];
    float4 b1 = *(const float4*)&brow[4];
    float4 b2 = *(const float4*)&brow[8];
    float4 b3 = *(const float4*)&brow[12];
    float4 c0 = *(const float4*)&crow[0];
    float4 c1 = *(const float4*)&crow[4];
    float4 c2 = *(const float4*)&crow[8];
    float4 c3 = *(const float4*)&crow[12];
    float uv  = bf2f(wv0 & 0xFFFFu);
    float dtv = bf2f(wv0 >> 16);
    f32x2 B2[8] = {{b0.x,b0.y},{b0.z,b0.w},{b1.x,b1.y},{b1.z,b1.w},
                   {b2.x,b2.y},{b2.z,b2.w},{b3.x,b3.y},{b3.z,b3.w}};
    f32x2 C2[8] = {{c0.x,c0.y},{c0.z,c0.w},{c1.x,c1.y},{c1.z,c1.w},
                   {c2.x,c2.y},{c2.z,c2.w},{c3.x,c3.y},{c3.z,c3.w}};
    float du = dtv * uv;
    f32x2 du2 = {du, du};
    f32x2 y2 = {0.f, 0.f};
    if (fast) {
      float e1 = __expf(-dtv);
      float e2 = e1 * e1;
      f32x2 dA = {e1, e2};
      f32x2 e22 = {e2, e2};
#pragma unroll
      for (int jj = 0; jj < 8; ++jj) {
        h2[jj] = dA * h2[jj] + du2 * B2[jj];
        y2 = y2 + h2[jj] * C2[jj];
        dA = dA * e22;
      }
    } else {
#pragma unroll
      for (int j = 0; j < 16; ++j) {
        float dA = __expf(dtv * a[j]);
        float hh = fmaf(dA, h2[j >> 1][j & 1], du * B2[j >> 1][j & 1]);
        h2[j >> 1][j & 1] = hh;
        y2[j & 1] = fmaf(hh, C2[j >> 1][j & 1], y2[j & 1]);
      }
    }
    float y = y2.x + y2.y;
    float zs = bf2f((unsigned int)zv0);
    smA[(chh * CH + ll) * 264 + d] = f2bf(fmaf(uv, dskv, y) * zs);   // ya, bf16
  }
  // -------- epilogue (ALL 8 waves): out_proj -> LN -> fc -> ReLU --------
  const int q = l >> 4, col = l & 15;
  const int rw = w & 3, np = w >> 2;          // row-group x channel-half
  ffrag acc[2][2];
  for (int nt2 = 0; nt2 < 2; ++nt2) {
    __syncthreads();           // iter0: ya complete; iter1: prior smB reads done
    for (int i = t; i < 64 * 32; i += 512) {
      int row = i >> 5, c8 = (i & 31) << 3;
      *(uint4*)&smB[row * 264 + c8] = *(const uint4*)&ow_b[((nt2 << 6) + row) * 256 + c8];
    }
    __syncthreads();
#pragma unroll
    for (int nt = 0; nt < 2; ++nt) acc[nt2][nt] = (ffrag){0.f, 0.f, 0.f, 0.f};
#pragma unroll
    for (int s8 = 0; s8 < 8; ++s8) {
      int k0 = s8 * 32 + q * 8;
      bfrag af = *(const bfrag*)&smA[((rw << 4) + col) * 264 + k0];
#pragma unroll
      for (int nt = 0; nt < 2; ++nt) {
        bfrag bf_ = *(const bfrag*)&smB[((((np << 1) + nt) << 4) + col) * 264 + k0];
        acc[nt2][nt] = __builtin_amdgcn_mfma_f32_16x16x32_bf16(af, bf_, acc[nt2][nt], 0, 0, 0);
      }
    }
  }
  float s1v[4], s2v[4];
#pragma unroll
  for (int i = 0; i < 4; ++i) {
    float s1 = 0.f, s2 = 0.f;
#pragma unroll
    for (int nt2 = 0; nt2 < 2; ++nt2)
#pragma unroll
      for (int nt = 0; nt < 2; ++nt) {
        float v = acc[nt2][nt][i];
        s1 += v; s2 = fmaf(v, v, s2);
      }
    s1 += __shfl_xor(s1, 1); s2 += __shfl_xor(s2, 1);
    s1 += __shfl_xor(s1, 2); s2 += __shfl_xor(s2, 2);
    s1 += __shfl_xor(s1, 4); s2 += __shfl_xor(s2, 4);
    s1 += __shfl_xor(s1, 8); s2 += __shfl_xor(s2, 8);
    s1v[i] = s1; s2v[i] = s2;
  }
  if (col == 0) {
#pragma unroll
    for (int i = 0; i < 4; ++i) {
      int r = (rw << 4) + (q << 2) + i;
      pS1[(np << 6) + r] = s1v[i];
      pS2[(np << 6) + r] = s2v[i];
    }
  }
  __syncthreads();   // partials ready; all smA(ya)/smB(ow) reads done
  float mu[4], rs[4];
#pragma unroll
  for (int i = 0; i < 4; ++i) {
    int r = (rw << 4) + (q << 2) + i;
    float s1 = pS1[r] + pS1[64 + r];
    float s2 = pS2[r] + pS2[64 + r];
    mu[i] = s1 * (1.f / DM);
    float var = s2 * (1.f / DM) - mu[i] * mu[i];
    rs[i] = rsqrtf(var + 1e-5f);
  }
#pragma unroll
  for (int nt2 = 0; nt2 < 2; ++nt2)
#pragma unroll
    for (int nt = 0; nt < 2; ++nt) {
      int n = (nt2 << 6) + ((((np << 1) + nt)) << 4) + col;
      float g = gamma[n], be = beta[n];
#pragma unroll
      for (int i = 0; i < 4; ++i) {
        int r = (rw << 4) + (q << 2) + i;
        smA[r * 136 + n] = f2bf(fmaf((acc[nt2][nt][i] - mu[i]) * rs[i], g, be));
      }
    }
  for (int i = t; i < 128 * 16; i += 512) {
    int row = i >> 4, c8 = (i & 15) << 3;
    *(uint4*)&smB[row * 136 + c8] = *(const uint4*)&fcw_b[row * 128 + c8];
  }
  __syncthreads();
  ffrag a2[4] = {{0.f,0.f,0.f,0.f},{0.f,0.f,0.f,0.f},{0.f,0.f,0.f,0.f},{0.f,0.f,0.f,0.f}};
#pragma unroll
  for (int s8 = 0; s8 < 4; ++s8) {
    int k0 = s8 * 32 + q * 8;
    bfrag af = *(const bfrag*)&smA[((rw << 4) + col) * 136 + k0];
#pragma unroll
    for (int nt = 0; nt < 4; ++nt) {
      bfrag bf_ = *(const bfrag*)&smB[((((np << 2) + nt) << 4) + col) * 136 + k0];
      a2[nt] = __builtin_amdgcn_mfma_f32_16x16x32_bf16(af, bf_, a2[nt], 0, 0, 0);
    }
  }
#pragma unroll
  for (int nt = 0; nt < 4; ++nt)
#pragma unroll
    for (int i = 0; i < 4; ++i) {
      int ml = (rw << 4) + (q << 2) + i;
      out[(base + ml) * 128 + (((np << 2) + nt) << 4) + col] = fmaxf(a2[nt][i], 0.f);
    }
}

extern "C" void kernel_launch(void* const* d_in, const int* in_sizes, int n_in,
                              void* d_out, int out_size, void* d_ws, size_t ws_size,
                              hipStream_t stream) {
  (void)in_sizes; (void)n_in; (void)out_size; (void)ws_size;
  const float* s    = (const float*)d_in[0];
  const float* w_in = (const float*)d_in[1];
  const float* cw   = (const float*)d_in[2];
  const float* cb   = (const float*)d_in[3];
  const float* xw   = (const float*)d_in[4];
  const float* dtw  = (const float*)d_in[5];
  const float* dtpb = (const float*)d_in[6];
  const float* alog = (const float*)d_in[7];
  const float* dsk  = (const float*)d_in[8];
  const float* ow   = (const float*)d_in[9];
  const float* gam  = (const float*)d_in[10];
  const float* bet  = (const float*)d_in[11];
  const float* fcw  = (const float*)d_in[12];
  float* out = (float*)d_out;
  float* ws  = (float*)d_ws;

  // float-unit offsets; all regions disjoint (audited r6; bf16 regions sized
  // as (num bf16 values)/2 floats):
  unsigned short* zsb  = (unsigned short*)(ws + 4194304);     // [4194304, 8388608)
  unsigned int*   udt  = (unsigned int*)(ws + 8388608);       // [8388608, 16777216)
  float*          Bb   = ws + 16777216;                       // [16777216, 17301504)
  float*          Cb   = ws + 17301504;                       // [17301504, 17825792)
  unsigned short* cP   = (unsigned short*)(ws + 17825792);    // [17825792, 19922944)
  unsigned short* cHe  = (unsigned short*)(ws + 19922944);    // [19922944, 22020096)
  unsigned short* w_in_b = (unsigned short*)(ws + 22020096);  // 65536 bf16 -> [22020096, 22052864)
  unsigned short* xw_b   = (unsigned short*)(ws + 22052864);  // 10240 bf16 -> [22052864, 22057984)
  unsigned short* ow_b   = (unsigned short*)(ws + 22057984);  // 32768 bf16 -> [22057984, 22074368)
  unsigned short* fcw_b  = (unsigned short*)(ws + 22074368);  // 16384 bf16 -> [22074368, 22082560)

  // 0. one-shot weight f32->bf16 (identical RNE)
  prep_weights<<<122, 256, 0, stream>>>(w_in, xw, ow, fcw, w_in_b, xw_b, ow_b, fcw_b);
  // 1. MEGA-FUSED front end: 1024 x 256 (1 chunk/block, 4 blocks/CU)
  xproj_dtproj<<<M_ / CH, 256, 0, stream>>>(s, w_in_b, xw_b, dtw, dtpb, cw, cb, alog,
                                            Bb, Cb, udt, zsb, cP, cHe);
  // 2. inter-chunk combine
  scan_combine<<<512, 512, 0, stream>>>(cP, cHe);
  // 3. FUSED scan phase 3 + out_proj + LN + fc + ReLU (depth-4 prefetch)
  scan3_out_ln_fc<<<B_ * NC / 2, 512, 0, stream>>>(udt, Bb, Cb, alog, cP, dsk, zsb,
                                                   ow_b, gam, bet, fcw_b, out);
}

// Round 13
// 168.785 us; speedup vs baseline: 1.1288x; 1.0085x over previous
//
#include <hip/hip_runtime.h>
#include <math.h>

#define B_ 8
#define L_ 4096
#define DM 128
#define DI 256
#define DSN 16
#define RK 8
#define M_ (B_*L_)      // 32768 positions
#define NC 128          // number of scan chunks
#define CH 32           // chunk length (NC*CH == L_)
#define CH2 64          // fused phase3 tile: 2 chunks

typedef __attribute__((ext_vector_type(8))) short bfrag;   // 8 bf16 (4 VGPRs)
typedef __attribute__((ext_vector_type(4))) float ffrag;   // 4 fp32 acc
typedef __attribute__((ext_vector_type(2))) float f32x2;   // packed-math pair

__device__ __forceinline__ float silu_f(float x) {
  return x * __builtin_amdgcn_rcpf(1.f + __expf(-x));
}
__device__ __forceinline__ float softplus_f(float x) {
  return (x > 20.f) ? x : __logf(1.f + __expf(x));
}

__device__ __forceinline__ unsigned short f2bf(float f) {
  unsigned int u = __builtin_bit_cast(unsigned int, f);
  unsigned int r = (u + 0x7FFFu + ((u >> 16) & 1u)) >> 16;   // RNE
  return (unsigned short)r;
}
__device__ __forceinline__ unsigned int f2bf2(float lo, float hi) {
  return (unsigned int)f2bf(lo) | ((unsigned int)f2bf(hi) << 16);
}
__device__ __forceinline__ float bf2f(unsigned int us) {
  return __builtin_bit_cast(float, us << 16);
}

// ---------------------------------------------------------------------------
// One-shot weight prep: f32 -> bf16 (same RNE -> bit-identical), plus dtw
// zero-padded K=8 -> K=32 bf16 (dtwb) so dt_proj runs as ONE MFMA step.
// ---------------------------------------------------------------------------
__global__ __launch_bounds__(256)
void prep_weights(const float* __restrict__ w_in, const float* __restrict__ xw,
                  const float* __restrict__ ow, const float* __restrict__ fcw,
                  const float* __restrict__ dtw,
                  unsigned short* __restrict__ w_in_b, unsigned short* __restrict__ xw_b,
                  unsigned short* __restrict__ ow_b, unsigned short* __restrict__ fcw_b,
                  unsigned short* __restrict__ dtwb) {
  const int i = blockIdx.x * 256 + threadIdx.x;
  if (i < 31232) {
    const float* src; unsigned short* dst; int j;
    if (i < 16384)      { src = w_in; dst = w_in_b; j = i; }           // 512x128
    else if (i < 18944) { src = xw;   dst = xw_b;   j = i - 16384; }   // 40x256
    else if (i < 27136) { src = ow;   dst = ow_b;   j = i - 18944; }   // 128x256
    else                { src = fcw;  dst = fcw_b;  j = i - 27136; }   // 128x128
    float4 v = *(const float4*)&src[j << 2];
    uint2 p = {f2bf2(v.x, v.y), f2bf2(v.z, v.w)};
    *(uint2*)&dst[j << 2] = p;
  } else if (i < 33280) {
    // dtwb: 256 ch x 32 K (K>=8 zero), 4 outputs per thread
    const int j = i - 31232;          // 0..2047
    const int ch = j >> 3, k4 = (j & 7) << 2;
    uint2 p = {0u, 0u};
    if (k4 < 8) {
      float4 v = *(const float4*)&dtw[ch * 8 + k4];
      p.x = f2bf2(v.x, v.y); p.y = f2bf2(v.z, v.w);
    }
    *(uint2*)&dtwb[ch * 32 + k4] = p;
  }
}

// ---------------------------------------------------------------------------
// MEGA-FUSED front end (r10 structure + dt-MFMA tail diet):
// 1024 blocks x 256 threads, 1 chunk/block, 4 blocks/CU.
// NEW: dt_proj = single K=32 MFMA phase (dtwb zero-padded); softplus + udt
// pack run in the MFMA epilogue; dt lands in LDS (dts, overlays dead hx) so
// the serial tail reads 1 LDS b16 instead of {8 FMA + 2 b128 + softplus +
// pack + global store} per iteration. No global readback (r11's mistake).
// LDS pool 37.9 KB: [As|ua 16.9K][hx|dts 18.5K][dtr_b 0.5K][Bs_l 2K].
// ---------------------------------------------------------------------------
__global__ __launch_bounds__(256, 4)
void xproj_dtproj(const float* __restrict__ s, const unsigned short* __restrict__ w_in_b,
                  const unsigned short* __restrict__ xw_b,
                  const unsigned short* __restrict__ dtwb,
                  const float* __restrict__ dtpb,
                  const float* __restrict__ cw, const float* __restrict__ cb,
                  const float* __restrict__ alog,
                  float* __restrict__ Bb, float* __restrict__ Cb,
                  unsigned int* __restrict__ udt,
                  unsigned short* __restrict__ zsb,
                  unsigned short* __restrict__ cP, unsigned short* __restrict__ cHe) {
  __shared__ __align__(16) char pool[37936];
  unsigned short* As = (unsigned short*)pool;              // 48*136*2 = 13056
  unsigned short* ua = (unsigned short*)pool;              // 32*264*2 = 16896 (overlay As)
  unsigned short* hx = (unsigned short*)(pool + 16896);    // 35*264*2 = 18480
  unsigned short* dts = (unsigned short*)(pool + 16896);   // 32*264*2 = 16896 (overlay hx)
  unsigned short* dtr_b = (unsigned short*)(pool + 35376); // 32*8*2   = 512
  float* Bs_l  = (float*)(pool + 35888);                   // 32*16*4  = 2048
  const int t = threadIdx.x;
  const int p0 = blockIdx.x << 5;             // 32-position tile = one chunk
  const int w = t >> 6, l = t & 63, q = l >> 4, col = l & 15;

  // ---- stage A (32 main rows + 16 halo rows of s, f32 -> bf16) ----
  for (int i = t; i < 48 * 32; i += 256) {
    int row = i >> 5, c4 = i & 31;
    int pos = (row < 32) ? (p0 + row) : (p0 - 16 + (row - 32));
    if (pos < 0) pos = 0;                     // block 0 halo: clamped, masked later
    float4 av = *(const float4*)&s[pos * 128 + (c4 << 2)];
    uint2 ap = {f2bf2(av.x, av.y), f2bf2(av.z, av.w)};
    *(uint2*)&As[row * 136 + (c4 << 2)] = ap;
  }
  __syncthreads();
  // ---- in_proj: tile stream; W fragments direct from global ----
  for (int jt = 0; jt < 8; ++jt) {
    const int wrow0 = jt << 6;
    const int T = (jt < 4) ? 12 : 8;
    for (int tile = w; tile < T; tile += 4) {
      const int mt = tile >> 2, nt = tile & 3;
      ffrag acc = {0.f, 0.f, 0.f, 0.f};
#pragma unroll
      for (int s8 = 0; s8 < 4; ++s8) {
        int k0 = s8 * 32 + q * 8;
        bfrag af = *(const bfrag*)&As[((mt << 4) + col) * 136 + k0];
        bfrag wf = *(const bfrag*)&w_in_b[(wrow0 + (nt << 4) + col) * 128 + k0];
        acc = __builtin_amdgcn_mfma_f32_16x16x32_bf16(wf, af, acc, 0, 0, 0);
      }
      const int chb = (nt << 4) + (q << 2);
      if (jt < 4) {
        uint2 pk = {f2bf2(acc[0], acc[1]), f2bf2(acc[2], acc[3])};
        const int ch = (jt << 6) + chb;
        if (mt < 2) {
          *(uint2*)&hx[(3 + (mt << 4) + col) * 264 + ch] = pk;
        } else if (col >= 13) {               // halo rows: positions p0-3..p0-1
          *(uint2*)&hx[(col - 13) * 264 + ch] = pk;
        }
      } else {
        uint2 pk = {f2bf2(silu_f(acc[0]), silu_f(acc[1])),
                    f2bf2(silu_f(acc[2]), silu_f(acc[3]))};
        const int m = p0 + (mt << 4) + col;
        *(uint2*)&zsb[m * 256 + ((jt - 4) << 6) + chb] = pk;
      }
    }
  }
  __syncthreads();   // hx complete; As reads done (ua overlay next)
  // ---- conv(4)+SiLU from hx (LDS) -> ua; thread = channel ----
  {
    const int k = t;
    const int lb = p0 & (L_ - 1);
    const float w0 = cw[k*4], w1 = cw[k*4+1], w2 = cw[k*4+2], w3 = cw[k*4+3];
    const float bias = cb[k];
    float x0 = (lb >= 3) ? bf2f((unsigned int)hx[0 * 264 + k]) : 0.f;
    float x1 = (lb >= 2) ? bf2f((unsigned int)hx[1 * 264 + k]) : 0.f;
    float x2 = (lb >= 1) ? bf2f((unsigned int)hx[2 * 264 + k]) : 0.f;
#pragma unroll 8
    for (int it = 0; it < 32; ++it) {
      float x3 = bf2f((unsigned int)hx[(3 + it) * 264 + k]);
      float u = silu_f(fmaf(w0, x0, fmaf(w1, x1, fmaf(w2, x2, fmaf(w3, x3, bias)))));
      ua[it * 264 + k] = f2bf(u);
      x0 = x1; x1 = x2; x2 = x3;
    }
  }
  __syncthreads();
  // ---- x_proj MFMA: 6 tiles (2 m x 3 n) over 4 waves; xw direct ----
  for (int tile = w; tile < 6; tile += 4) {
    const int mt = tile & 1, nt = tile >> 1;
    ffrag acc = {0.f, 0.f, 0.f, 0.f};
#pragma unroll
    for (int s8 = 0; s8 < 8; ++s8) {
      int k0 = s8 * 32 + q * 8;
      bfrag af = *(const bfrag*)&ua[((mt << 4) + col) * 264 + k0];
      const int nrow = (nt << 4) + col;
      bfrag wf = {0, 0, 0, 0, 0, 0, 0, 0};
      if (nrow < 40) wf = *(const bfrag*)&xw_b[nrow * 256 + k0];
      acc = __builtin_amdgcn_mfma_f32_16x16x32_bf16(wf, af, acc, 0, 0, 0);
    }
    const int ml = (mt << 4) + col;
    const int m = p0 + ml;
    const int n0 = (nt << 4) + (q << 2);
    if (n0 < 8) {
      uint2 dp = {f2bf2(acc[0], acc[1]), f2bf2(acc[2], acc[3])};
      *(uint2*)&dtr_b[ml * 8 + n0] = dp;      // dtr as bf16 (MFMA A-operand rows)
    } else if (n0 < 24) {
      float4 v = {acc[0], acc[1], acc[2], acc[3]};
      *(float4*)&Bb[m * 16 + (n0 - 8)] = v;
      *(float4*)&Bs_l[ml * 16 + (n0 - 8)] = v;
    } else if (n0 < 40) {
      float4 v = {acc[0], acc[1], acc[2], acc[3]};
      *(float4*)&Cb[m * 16 + (n0 - 24)] = v;
    }                                         // n0 >= 40: zero rows, drop
  }
  __syncthreads();   // dtr_b ready; conv's hx reads long done (dts overlay ok)
  // ---- dt MFMA: 2 pos-tiles x 16 ch-tiles, ONE K=32 step each ----
  // dtwb rows are zero for k>=8, so af's k>=8 contents are don't-care.
  for (int tile = w; tile < 32; tile += 4) {
    const int mt = tile & 1, ntc = tile >> 1;
    bfrag af = *(const bfrag*)&dtr_b[((mt << 4) + col) * 8];
    bfrag wf = *(const bfrag*)&dtwb[((ntc << 4) + col) * 32 + (q << 3)];
    ffrag acc = {0.f, 0.f, 0.f, 0.f};
    acc = __builtin_amdgcn_mfma_f32_16x16x32_bf16(wf, af, acc, 0, 0, 0);
    const int pos = (mt << 4) + col;
    const int ch0 = (ntc << 4) + (q << 2);
    float4 bia = *(const float4*)&dtpb[ch0];
    float d0 = softplus_f(acc[0] + bia.x);
    float d1 = softplus_f(acc[1] + bia.y);
    float d2 = softplus_f(acc[2] + bia.z);
    float d3 = softplus_f(acc[3] + bia.w);
    unsigned short b0 = f2bf(d0), b1 = f2bf(d1), b2 = f2bf(d2), b3 = f2bf(d3);
    unsigned long long uq4 = *(const unsigned long long*)&ua[pos * 264 + ch0];
    uint4 pk;
    pk.x = (unsigned int)(unsigned short)(uq4)       | ((unsigned int)b0 << 16);
    pk.y = (unsigned int)(unsigned short)(uq4 >> 16) | ((unsigned int)b1 << 16);
    pk.z = (unsigned int)(unsigned short)(uq4 >> 32) | ((unsigned int)b2 << 16);
    pk.w = (unsigned int)(unsigned short)(uq4 >> 48) | ((unsigned int)b3 << 16);
    *(uint4*)&udt[(p0 + pos) * 256 + ch0] = pk;
    uint2 dpk = {(unsigned int)b0 | ((unsigned int)b1 << 16),
                 (unsigned int)b2 | ((unsigned int)b3 << 16)};
    *(uint2*)&dts[pos * 264 + ch0] = dpk;     // dt bf16 for the tail (LDS)
  }
  __syncthreads();
  // ---- inline scan phase 1 (thread = channel; dt/u from LDS) ----
  {
    const int d = t;
    const int bb = p0 >> 12;
    const int cc = (p0 & (L_ - 1)) >> 5;
    const int bc = bb * NC + cc;
    float a[16];
    bool okl = true;
#pragma unroll
    for (int j = 0; j < 16; ++j) {
      a[j] = -__expf(alog[d * 16 + j]);
      float tgt = (float)(j + 1);
      okl = okl && (fabsf(a[j] + tgt) <= 1e-3f * tgt);
    }
    const bool fast = (bool)__all((int)okl);
    f32x2 h2[8] = {{0.f,0.f},{0.f,0.f},{0.f,0.f},{0.f,0.f},
                   {0.f,0.f},{0.f,0.f},{0.f,0.f},{0.f,0.f}};
    float sdt = 0.f;
#pragma unroll 2
    for (int pp = 0; pp < 32; ++pp) {
      float dtv = bf2f((unsigned int)dts[pp * 264 + d]);
      float uv  = bf2f((unsigned int)ua[pp * 264 + d]);
      float du = dtv * uv;
      sdt += dtv;
      const float* brow = &Bs_l[pp * 16];
      float4 b0 = *(const float4*)&brow[0];
      float4 b1 = *(const float4*)&brow[4];
      float4 b2 = *(const float4*)&brow[8];
      float4 b3 = *(const float4*)&brow[12];
      f32x2 B2[8] = {{b0.x,b0.y},{b0.z,b0.w},{b1.x,b1.y},{b1.z,b1.w},
                     {b2.x,b2.y},{b2.z,b2.w},{b3.x,b3.y},{b3.z,b3.w}};
      f32x2 du2 = {du, du};
      if (fast) {
        float e1 = __expf(-dtv);
        float e2 = e1 * e1;
        f32x2 dA = {e1, e2};
        f32x2 e22 = {e2, e2};
#pragma unroll
        for (int jj = 0; jj < 8; ++jj) {
          h2[jj] = dA * h2[jj] + du2 * B2[jj];
          dA = dA * e22;
        }
      } else {
#pragma unroll
        for (int j = 0; j < 16; ++j) {
          float dA = __expf(dtv * a[j]);
          h2[j >> 1][j & 1] = fmaf(dA, h2[j >> 1][j & 1], du * B2[j >> 1][j & 1]);
        }
      }
    }
#pragma unroll
    for (int j = 0; j < 16; ++j) {
      int o = (bc * 16 + j) * 256 + d;
      cP[o]  = f2bf(__expf(a[j] * sdt));
      cHe[o] = f2bf(h2[j >> 1][j & 1]);
    }
  }
}

// ---------------------------------------------------------------------------
// Hierarchical combine (NC=128, bf16): 512 thr = 64 sd x 8 segments of 16.
// ---------------------------------------------------------------------------
__global__ __launch_bounds__(512)
void scan_combine(unsigned short* __restrict__ cP, const unsigned short* __restrict__ cHe) {
  __shared__ float segP[64 * 9], segH[64 * 9], segS[64 * 9];
  const int t = threadIdx.x;
  const int sdl = t & 63, seg = t >> 6;
  const int blk = blockIdx.x;
  const int b = blk >> 6, grp = blk & 63;
  const int sd = (grp << 6) + sdl;
  const int base = b * NC * 4096 + sd;
  float Pacc = 1.f, Hacc = 0.f;
#pragma unroll
  for (int i = 0; i < 16; ++i) {
    int idx = base + (seg * 16 + i) * 4096;
    float p = bf2f((unsigned int)cP[idx]);
    float he = bf2f((unsigned int)cHe[idx]);
    Hacc = fmaf(p, Hacc, he);
    Pacc *= p;
  }
  segP[sdl * 9 + seg] = Pacc;
  segH[sdl * 9 + seg] = Hacc;
  __syncthreads();
  if (t < 64) {
    float hs = 0.f;
#pragma unroll
    for (int s2 = 0; s2 < 8; ++s2) {
      segS[t * 9 + s2] = hs;
      hs = fmaf(segP[t * 9 + s2], hs, segH[t * 9 + s2]);
    }
  }
  __syncthreads();
  float hs = segS[sdl * 9 + seg];
#pragma unroll
  for (int i = 0; i < 16; ++i) {
    int idx = base + (seg * 16 + i) * 4096;
    float p = bf2f((unsigned int)cP[idx]);
    float he = bf2f((unsigned int)cHe[idx]);
    cP[idx] = f2bf(hs);
    hs = fmaf(p, hs, he);
  }
}

// ---------------------------------------------------------------------------
// FUSED scan phase 3 + out_proj + LayerNorm + fc + ReLU (r10 exact:
// depth-2 prefetch restored — depth-4 was neutral-negative in r12).
// ---------------------------------------------------------------------------
__global__ __launch_bounds__(512, 4)
void scan3_out_ln_fc(const unsigned int* __restrict__ udt,
                     const float* __restrict__ Bb, const float* __restrict__ Cb,
                     const float* __restrict__ alog, const unsigned short* __restrict__ hst,
                     const float* __restrict__ dsk,
                     const unsigned short* __restrict__ zsb,
                     const unsigned short* __restrict__ ow_b,
                     const float* __restrict__ gamma, const float* __restrict__ beta,
                     const unsigned short* __restrict__ fcw_b, float* __restrict__ out) {
  __shared__ float Bs[CH2 * 16];             // 4 KB
  __shared__ float Cs[CH2 * 16];             // 4 KB
  __shared__ unsigned short smA[64 * 264];   // ya (stride 264); later hnb (stride 136)
  __shared__ unsigned short smB[128 * 136];  // ow half (stride 264); later fcw (136)
  __shared__ float pS1[128], pS2[128];       // LN cross-wave partials [np*64+row]
  const int bc = blockIdx.x;
  const int b = bc >> 6, cc = bc & 63;
  const int t = threadIdx.x;
  const int l = t & 63, w = t >> 6;
  const int chh = t >> 8;                     // which of the 2 parallel chunks
  const int d = t & 255;                      // channel
  const int base = b * L_ + (cc << 1) * CH;   // 64-position tile start
  const int cbase = base + chh * CH;          // this chunk's start
  const int hc = b * NC + (cc << 1) + chh;    // h_start chunk index
  if (t < CH2 * 4)           ((float4*)Bs)[t]            = *(const float4*)&Bb[base * 16 + (t << 2)];
  else if (t < CH2 * 8)      ((float4*)Cs)[t - CH2 * 4]  = *(const float4*)&Cb[base * 16 + ((t - CH2 * 4) << 2)];
  float a[16];
  bool okl = true;
#pragma unroll
  for (int j = 0; j < 16; ++j) {
    a[j] = -__expf(alog[d * 16 + j]);
    float tgt = (float)(j + 1);
    okl = okl && (fabsf(a[j] + tgt) <= 1e-3f * tgt);
  }
  const bool fast = (bool)__all((int)okl);
  const float dskv = dsk[d];
  f32x2 h2[8];
#pragma unroll
  for (int jj = 0; jj < 8; ++jj) {
    h2[jj][0] = bf2f((unsigned int)hst[(hc * 16 + (jj << 1)) * 256 + d]);
    h2[jj][1] = bf2f((unsigned int)hst[(hc * 16 + (jj << 1) + 1) * 256 + d]);
  }
  unsigned int wv0 = udt[cbase * 256 + d];
  unsigned int wv1 = udt[(cbase + 1) * 256 + d];
  unsigned short zv0 = zsb[cbase * 256 + d];
  unsigned short zv1 = zsb[(cbase + 1) * 256 + d];
  __syncthreads();
#pragma unroll 2
  for (int ll = 0; ll < CH; ++ll) {
    const int l2 = (ll + 2 < CH) ? ll + 2 : CH - 1;
    unsigned int wv2 = udt[(cbase + l2) * 256 + d];
    unsigned short zv2 = zsb[(cbase + l2) * 256 + d];
    const float* brow = &Bs[(chh * CH + ll) * 16];
    const float* crow = &Cs[(chh * CH + ll) * 16];
    float4 b0 = *(const float4*)&brow[0];
    float4 b1 = *(const float4*)&brow[4];
    float4 b2 = *(const float4*)&brow[8];
    float4 b3 = *(const float4*)&brow[12];
    float4 c0 = *(const float4*)&crow[0];
    float4 c1 = *(const float4*)&crow[4];
    float4 c2 = *(const float4*)&crow[8];
    float4 c3 = *(const float4*)&crow[12];
    float uv  = bf2f(wv0 & 0xFFFFu);
    float dtv = bf2f(wv0 >> 16);
    f32x2 B2[8] = {{b0.x,b0.y},{b0.z,b0.w},{b1.x,b1.y},{b1.z,b1.w},
                   {b2.x,b2.y},{b2.z,b2.w},{b3.x,b3.y},{b3.z,b3.w}};
    f32x2 C2[8] = {{c0.x,c0.y},{c0.z,c0.w},{c1.x,c1.y},{c1.z,c1.w},
                   {c2.x,c2.y},{c2.z,c2.w},{c3.x,c3.y},{c3.z,c3.w}};
    float du = dtv * uv;
    f32x2 du2 = {du, du};
    f32x2 y2 = {0.f, 0.f};
    if (fast) {
      float e1 = __expf(-dtv);
      float e2 = e1 * e1;
      f32x2 dA = {e1, e2};
      f32x2 e22 = {e2, e2};
#pragma unroll
      for (int jj = 0; jj < 8; ++jj) {
        h2[jj] = dA * h2[jj] + du2 * B2[jj];
        y2 = y2 + h2[jj] * C2[jj];
        dA = dA * e22;
      }
    } else {
#pragma unroll
      for (int j = 0; j < 16; ++j) {
        float dA = __expf(dtv * a[j]);
        float hh = fmaf(dA, h2[j >> 1][j & 1], du * B2[j >> 1][j & 1]);
        h2[j >> 1][j & 1] = hh;
        y2[j & 1] = fmaf(hh, C2[j >> 1][j & 1], y2[j & 1]);
      }
    }
    float y = y2.x + y2.y;
    float zs = bf2f((unsigned int)zv0);
    smA[(chh * CH + ll) * 264 + d] = f2bf(fmaf(uv, dskv, y) * zs);   // ya, bf16
    wv0 = wv1; wv1 = wv2; zv0 = zv1; zv1 = zv2;
  }
  // -------- epilogue (ALL 8 waves): out_proj -> LN -> fc -> ReLU --------
  const int q = l >> 4, col = l & 15;
  const int rw = w & 3, np = w >> 2;          // row-group x channel-half
  ffrag acc[2][2];
  for (int nt2 = 0; nt2 < 2; ++nt2) {
    __syncthreads();           // iter0: ya complete; iter1: prior smB reads done
    for (int i = t; i < 64 * 32; i += 512) {
      int row = i >> 5, c8 = (i & 31) << 3;
      *(uint4*)&smB[row * 264 + c8] = *(const uint4*)&ow_b[((nt2 << 6) + row) * 256 + c8];
    }
    __syncthreads();
#pragma unroll
    for (int nt = 0; nt < 2; ++nt) acc[nt2][nt] = (ffrag){0.f, 0.f, 0.f, 0.f};
#pragma unroll
    for (int s8 = 0; s8 < 8; ++s8) {
      int k0 = s8 * 32 + q * 8;
      bfrag af = *(const bfrag*)&smA[((rw << 4) + col) * 264 + k0];
#pragma unroll
      for (int nt = 0; nt < 2; ++nt) {
        bfrag bf_ = *(const bfrag*)&smB[((((np << 1) + nt) << 4) + col) * 264 + k0];
        acc[nt2][nt] = __builtin_amdgcn_mfma_f32_16x16x32_bf16(af, bf_, acc[nt2][nt], 0, 0, 0);
      }
    }
  }
  float s1v[4], s2v[4];
#pragma unroll
  for (int i = 0; i < 4; ++i) {
    float s1 = 0.f, s2 = 0.f;
#pragma unroll
    for (int nt2 = 0; nt2 < 2; ++nt2)
#pragma unroll
      for (int nt = 0; nt < 2; ++nt) {
        float v = acc[nt2][nt][i];
        s1 += v; s2 = fmaf(v, v, s2);
      }
    s1 += __shfl_xor(s1, 1); s2 += __shfl_xor(s2, 1);
    s1 += __shfl_xor(s1, 2); s2 += __shfl_xor(s2, 2);
    s1 += __shfl_xor(s1, 4); s2 += __shfl_xor(s2, 4);
    s1 += __shfl_xor(s1, 8); s2 += __shfl_xor(s2, 8);
    s1v[i] = s1; s2v[i] = s2;
  }
  if (col == 0) {
#pragma unroll
    for (int i = 0; i < 4; ++i) {
      int r = (rw << 4) + (q << 2) + i;
      pS1[(np << 6) + r] = s1v[i];
      pS2[(np << 6) + r] = s2v[i];
    }
  }
  __syncthreads();   // partials ready; all smA(ya)/smB(ow) reads done
  float mu[4], rs[4];
#pragma unroll
  for (int i = 0; i < 4; ++i) {
    int r = (rw << 4) + (q << 2) + i;
    float s1 = pS1[r] + pS1[64 + r];
    float s2 = pS2[r] + pS2[64 + r];
    mu[i] = s1 * (1.f / DM);
    float var = s2 * (1.f / DM) - mu[i] * mu[i];
    rs[i] = rsqrtf(var + 1e-5f);
  }
#pragma unroll
  for (int nt2 = 0; nt2 < 2; ++nt2)
#pragma unroll
    for (int nt = 0; nt < 2; ++nt) {
      int n = (nt2 << 6) + ((((np << 1) + nt)) << 4) + col;
      float g = gamma[n], be = beta[n];
#pragma unroll
      for (int i = 0; i < 4; ++i) {
        int r = (rw << 4) + (q << 2) + i;
        smA[r * 136 + n] = f2bf(fmaf((acc[nt2][nt][i] - mu[i]) * rs[i], g, be));
      }
    }
  for (int i = t; i < 128 * 16; i += 512) {
    int row = i >> 4, c8 = (i & 15) << 3;
    *(uint4*)&smB[row * 136 + c8] = *(const uint4*)&fcw_b[row * 128 + c8];
  }
  __syncthreads();
  ffrag a2[4] = {{0.f,0.f,0.f,0.f},{0.f,0.f,0.f,0.f},{0.f,0.f,0.f,0.f},{0.f,0.f,0.f,0.f}};
#pragma unroll
  for (int s8 = 0; s8 < 4; ++s8) {
    int k0 = s8 * 32 + q * 8;
    bfrag af = *(const bfrag*)&smA[((rw << 4) + col) * 136 + k0];
#pragma unroll
    for (int nt = 0; nt < 4; ++nt) {
      bfrag bf_ = *(const bfrag*)&smB[((((np << 2) + nt) << 4) + col) * 136 + k0];
      a2[nt] = __builtin_amdgcn_mfma_f32_16x16x32_bf16(af, bf_, a2[nt], 0, 0, 0);
    }
  }
#pragma unroll
  for (int nt = 0; nt < 4; ++nt)
#pragma unroll
    for (int i = 0; i < 4; ++i) {
      int ml = (rw << 4) + (q << 2) + i;
      out[(base + ml) * 128 + (((np << 2) + nt) << 4) + col] = fmaxf(a2[nt][i], 0.f);
    }
}

extern "C" void kernel_launch(void* const* d_in, const int* in_sizes, int n_in,
                              void* d_out, int out_size, void* d_ws, size_t ws_size,
                              hipStream_t stream) {
  (void)in_sizes; (void)n_in; (void)out_size; (void)ws_size;
  const float* s    = (const float*)d_in[0];
  const float* w_in = (const float*)d_in[1];
  const float* cw   = (const float*)d_in[2];
  const float* cb   = (const float*)d_in[3];
  const float* xw   = (const float*)d_in[4];
  const float* dtw  = (const float*)d_in[5];
  const float* dtpb = (const float*)d_in[6];
  const float* alog = (const float*)d_in[7];
  const float* dsk  = (const float*)d_in[8];
  const float* ow   = (const float*)d_in[9];
  const float* gam  = (const float*)d_in[10];
  const float* bet  = (const float*)d_in[11];
  const float* fcw  = (const float*)d_in[12];
  float* out = (float*)d_out;
  float* ws  = (float*)d_ws;

  // float-unit offsets; all regions disjoint (re-audited r13; bf16 regions
  // sized as (num bf16 values)/2 floats):
  unsigned short* zsb  = (unsigned short*)(ws + 4194304);     // [4194304, 8388608)
  unsigned int*   udt  = (unsigned int*)(ws + 8388608);       // [8388608, 16777216)
  float*          Bb   = ws + 16777216;                       // [16777216, 17301504)
  float*          Cb   = ws + 17301504;                       // [17301504, 17825792)
  unsigned short* cP   = (unsigned short*)(ws + 17825792);    // [17825792, 19922944)
  unsigned short* cHe  = (unsigned short*)(ws + 19922944);    // [19922944, 22020096)
  unsigned short* w_in_b = (unsigned short*)(ws + 22020096);  // 65536 bf16 -> [22020096, 22052864)
  unsigned short* xw_b   = (unsigned short*)(ws + 22052864);  // 10240 bf16 -> [22052864, 22057984)
  unsigned short* ow_b   = (unsigned short*)(ws + 22057984);  // 32768 bf16 -> [22057984, 22074368)
  unsigned short* fcw_b  = (unsigned short*)(ws + 22074368);  // 16384 bf16 -> [22074368, 22082560)
  unsigned short* dtwb   = (unsigned short*)(ws + 22082560);  //  8192 bf16 -> [22082560, 22086656)

  // 0. one-shot weight f32->bf16 + dtw zero-padded K=32 (dtwb)
  prep_weights<<<130, 256, 0, stream>>>(w_in, xw, ow, fcw, dtw,
                                        w_in_b, xw_b, ow_b, fcw_b, dtwb);
  // 1. MEGA-FUSED front end: in_proj + conv + x_proj + dt-MFMA + scan phase 1
  xproj_dtproj<<<M_ / CH, 256, 0, stream>>>(s, w_in_b, xw_b, dtwb, dtpb, cw, cb, alog,
                                            Bb, Cb, udt, zsb, cP, cHe);
  // 2. inter-chunk combine
  scan_combine<<<512, 512, 0, stream>>>(cP, cHe);
  // 3. FUSED scan phase 3 + out_proj + LN + fc + ReLU (r10 exact)
  scan3_out_ln_fc<<<B_ * NC / 2, 512, 0, stream>>>(udt, Bb, Cb, alog, cP, dsk, zsb,
                                                   ow_b, gam, bet, fcw_b, out);
}

// Round 15
// 166.821 us; speedup vs baseline: 1.1421x; 1.0118x over previous
//
#include <hip/hip_runtime.h>
#include <math.h>

#define B_ 8
#define L_ 4096
#define DM 128
#define DI 256
#define DSN 16
#define RK 8
#define M_ (B_*L_)      // 32768 positions
#define NC 128          // number of scan chunks
#define CH 32           // chunk length (NC*CH == L_)
#define CH2 64          // fused phase3 tile: 2 chunks

typedef __attribute__((ext_vector_type(8))) short bfrag;   // 8 bf16 (4 VGPRs)
typedef __attribute__((ext_vector_type(4))) float ffrag;   // 4 fp32 acc
typedef __attribute__((ext_vector_type(2))) float f32x2;   // packed-math pair

__device__ __forceinline__ float silu_f(float x) {
  return x * __builtin_amdgcn_rcpf(1.f + __expf(-x));
}
__device__ __forceinline__ float softplus_f(float x) {
  return (x > 20.f) ? x : __logf(1.f + __expf(x));
}

__device__ __forceinline__ unsigned short f2bf(float f) {
  unsigned int u = __builtin_bit_cast(unsigned int, f);
  unsigned int r = (u + 0x7FFFu + ((u >> 16) & 1u)) >> 16;   // RNE
  return (unsigned short)r;
}
__device__ __forceinline__ unsigned int f2bf2(float lo, float hi) {
  return (unsigned int)f2bf(lo) | ((unsigned int)f2bf(hi) << 16);
}
__device__ __forceinline__ float bf2f(unsigned int us) {
  return __builtin_bit_cast(float, us << 16);
}

// ---------------------------------------------------------------------------
// One-shot weight prep: f32 -> bf16 (same RNE -> bit-identical results).
// ---------------------------------------------------------------------------
__global__ __launch_bounds__(256)
void prep_weights(const float* __restrict__ w_in, const float* __restrict__ xw,
                  const float* __restrict__ ow, const float* __restrict__ fcw,
                  unsigned short* __restrict__ w_in_b, unsigned short* __restrict__ xw_b,
                  unsigned short* __restrict__ ow_b, unsigned short* __restrict__ fcw_b) {
  const int i = blockIdx.x * 256 + threadIdx.x;
  const float* src; unsigned short* dst; int j;
  if (i < 16384)      { src = w_in; dst = w_in_b; j = i; }           // 512x128
  else if (i < 18944) { src = xw;   dst = xw_b;   j = i - 16384; }   // 40x256
  else if (i < 27136) { src = ow;   dst = ow_b;   j = i - 18944; }   // 128x256
  else if (i < 31232) { src = fcw;  dst = fcw_b;  j = i - 27136; }   // 128x128
  else return;
  float4 v = *(const float4*)&src[j << 2];
  uint2 p = {f2bf2(v.x, v.y), f2bf2(v.z, v.w)};
  *(uint2*)&dst[j << 2] = p;
}

// ---------------------------------------------------------------------------
// MEGA-FUSED front end (r9/r10 structure — best measured): 1024 blocks x 256
// threads, 1 scan chunk per block, 4 blocks/CU. Weights direct from global.
// ---------------------------------------------------------------------------
__global__ __launch_bounds__(256, 4)
void xproj_dtproj(const float* __restrict__ s, const unsigned short* __restrict__ w_in_b,
                  const unsigned short* __restrict__ xw_b,
                  const float* __restrict__ dtw, const float* __restrict__ dtpb,
                  const float* __restrict__ cw, const float* __restrict__ cb,
                  const float* __restrict__ alog,
                  float* __restrict__ Bb, float* __restrict__ Cb,
                  unsigned int* __restrict__ udt,
                  unsigned short* __restrict__ zsb,
                  unsigned short* __restrict__ cP, unsigned short* __restrict__ cHe) {
  __shared__ __align__(16) char pool[38960];
  unsigned short* As = (unsigned short*)pool;              // 48*136*2 = 13056
  unsigned short* ua = (unsigned short*)pool;              // 32*264*2 = 16896 (overlay As)
  unsigned short* hx = (unsigned short*)(pool + 16896);    // 35*264*2 = 18480
  float* dtr_s = (float*)(pool + 35376);                   // 32*12*4  = 1536
  float* Bs_l  = (float*)(pool + 36912);                   // 32*16*4  = 2048
  const int t = threadIdx.x;
  const int p0 = blockIdx.x << 5;             // 32-position tile = one chunk
  const int w = t >> 6, l = t & 63, q = l >> 4, col = l & 15;

  // ---- stage A (32 main rows + 16 halo rows of s, f32 -> bf16) ----
  for (int i = t; i < 48 * 32; i += 256) {
    int row = i >> 5, c4 = i & 31;
    int pos = (row < 32) ? (p0 + row) : (p0 - 16 + (row - 32));
    if (pos < 0) pos = 0;                     // block 0 halo: clamped, masked later
    float4 av = *(const float4*)&s[pos * 128 + (c4 << 2)];
    uint2 ap = {f2bf2(av.x, av.y), f2bf2(av.z, av.w)};
    *(uint2*)&As[row * 136 + (c4 << 2)] = ap;
  }
  __syncthreads();
  // ---- in_proj: tile stream; W fragments direct from global ----
  for (int jt = 0; jt < 8; ++jt) {
    const int wrow0 = jt << 6;
    const int T = (jt < 4) ? 12 : 8;
    for (int tile = w; tile < T; tile += 4) {
      const int mt = tile >> 2, nt = tile & 3;
      ffrag acc = {0.f, 0.f, 0.f, 0.f};
#pragma unroll
      for (int s8 = 0; s8 < 4; ++s8) {
        int k0 = s8 * 32 + q * 8;
        bfrag af = *(const bfrag*)&As[((mt << 4) + col) * 136 + k0];
        bfrag wf = *(const bfrag*)&w_in_b[(wrow0 + (nt << 4) + col) * 128 + k0];
        acc = __builtin_amdgcn_mfma_f32_16x16x32_bf16(wf, af, acc, 0, 0, 0);
      }
      const int chb = (nt << 4) + (q << 2);
      if (jt < 4) {
        uint2 pk = {f2bf2(acc[0], acc[1]), f2bf2(acc[2], acc[3])};
        const int ch = (jt << 6) + chb;
        if (mt < 2) {
          *(uint2*)&hx[(3 + (mt << 4) + col) * 264 + ch] = pk;
        } else if (col >= 13) {               // halo rows: positions p0-3..p0-1
          *(uint2*)&hx[(col - 13) * 264 + ch] = pk;
        }
      } else {
        uint2 pk = {f2bf2(silu_f(acc[0]), silu_f(acc[1])),
                    f2bf2(silu_f(acc[2]), silu_f(acc[3]))};
        const int m = p0 + (mt << 4) + col;
        *(uint2*)&zsb[m * 256 + ((jt - 4) << 6) + chb] = pk;
      }
    }
  }
  __syncthreads();   // hx complete; As reads done (ua overlay next)
  // ---- conv(4)+SiLU from hx (LDS) -> ua; thread = channel ----
  {
    const int k = t;
    const int lb = p0 & (L_ - 1);
    const float w0 = cw[k*4], w1 = cw[k*4+1], w2 = cw[k*4+2], w3 = cw[k*4+3];
    const float bias = cb[k];
    float x0 = (lb >= 3) ? bf2f((unsigned int)hx[0 * 264 + k]) : 0.f;
    float x1 = (lb >= 2) ? bf2f((unsigned int)hx[1 * 264 + k]) : 0.f;
    float x2 = (lb >= 1) ? bf2f((unsigned int)hx[2 * 264 + k]) : 0.f;
#pragma unroll 8
    for (int it = 0; it < 32; ++it) {
      float x3 = bf2f((unsigned int)hx[(3 + it) * 264 + k]);
      float u = silu_f(fmaf(w0, x0, fmaf(w1, x1, fmaf(w2, x2, fmaf(w3, x3, bias)))));
      ua[it * 264 + k] = f2bf(u);
      x0 = x1; x1 = x2; x2 = x3;
    }
  }
  __syncthreads();
  // ---- x_proj MFMA: 6 tiles (2 m x 3 n) over 4 waves; xw direct ----
  for (int tile = w; tile < 6; tile += 4) {
    const int mt = tile & 1, nt = tile >> 1;
    ffrag acc = {0.f, 0.f, 0.f, 0.f};
#pragma unroll
    for (int s8 = 0; s8 < 8; ++s8) {
      int k0 = s8 * 32 + q * 8;
      bfrag af = *(const bfrag*)&ua[((mt << 4) + col) * 264 + k0];
      const int nrow = (nt << 4) + col;
      bfrag wf = {0, 0, 0, 0, 0, 0, 0, 0};
      if (nrow < 40) wf = *(const bfrag*)&xw_b[nrow * 256 + k0];
      acc = __builtin_amdgcn_mfma_f32_16x16x32_bf16(wf, af, acc, 0, 0, 0);
    }
    const int ml = (mt << 4) + col;
    const int m = p0 + ml;
    const int n0 = (nt << 4) + (q << 2);
    float4 v = {acc[0], acc[1], acc[2], acc[3]};
    if (n0 < 8) {
      *(float4*)&dtr_s[ml * 12 + n0] = v;
    } else if (n0 < 24) {
      *(float4*)&Bb[m * 16 + (n0 - 8)] = v;
      *(float4*)&Bs_l[ml * 16 + (n0 - 8)] = v;
    } else if (n0 < 40) {
      *(float4*)&Cb[m * 16 + (n0 - 24)] = v;
    }                                         // n0 >= 40: zero rows, drop
  }
  __syncthreads();
  // ---- dt_proj + softplus + inline scan phase 1 (thread = channel) ----
  {
    const int d = t;
    const int bb = p0 >> 12;
    const int cc = (p0 & (L_ - 1)) >> 5;
    const int bc = bb * NC + cc;
    float w8[8];
    *(float4*)&w8[0] = *(const float4*)&dtw[d * 8];
    *(float4*)&w8[4] = *(const float4*)&dtw[d * 8 + 4];
    const float bias = dtpb[d];
    float a[16];
    bool okl = true;
#pragma unroll
    for (int j = 0; j < 16; ++j) {
      a[j] = -__expf(alog[d * 16 + j]);
      float tgt = (float)(j + 1);
      okl = okl && (fabsf(a[j] + tgt) <= 1e-3f * tgt);
    }
    const bool fast = (bool)__all((int)okl);
    f32x2 h2[8] = {{0.f,0.f},{0.f,0.f},{0.f,0.f},{0.f,0.f},
                   {0.f,0.f},{0.f,0.f},{0.f,0.f},{0.f,0.f}};
    float sdt = 0.f;
#pragma unroll 2
    for (int pp = 0; pp < 32; ++pp) {
      float r0[8];
      *(float4*)&r0[0] = *(const float4*)&dtr_s[pp * 12];
      *(float4*)&r0[4] = *(const float4*)&dtr_s[pp * 12 + 4];
      float a2 = bias;
#pragma unroll
      for (int r2 = 0; r2 < 8; ++r2) a2 = fmaf(r0[r2], w8[r2], a2);
      float sp = softplus_f(a2);
      unsigned int uq = (unsigned int)ua[pp * 264 + d];
      unsigned short spb = f2bf(sp);
      udt[(p0 + pp) * 256 + d] = uq | ((unsigned int)spb << 16);
      float dtv = bf2f((unsigned int)spb);
      float uv  = bf2f(uq);
      float du = dtv * uv;
      sdt += dtv;
      const float* brow = &Bs_l[pp * 16];
      float4 b0 = *(const float4*)&brow[0];
      float4 b1 = *(const float4*)&brow[4];
      float4 b2 = *(const float4*)&brow[8];
      float4 b3 = *(const float4*)&brow[12];
      f32x2 B2[8] = {{b0.x,b0.y},{b0.z,b0.w},{b1.x,b1.y},{b1.z,b1.w},
                     {b2.x,b2.y},{b2.z,b2.w},{b3.x,b3.y},{b3.z,b3.w}};
      f32x2 du2 = {du, du};
      if (fast) {
        float e1 = __expf(-dtv);
        float e2 = e1 * e1;
        f32x2 dA = {e1, e2};
        f32x2 e22 = {e2, e2};
#pragma unroll
        for (int jj = 0; jj < 8; ++jj) {
          h2[jj] = dA * h2[jj] + du2 * B2[jj];
          dA = dA * e22;
        }
      } else {
#pragma unroll
        for (int j = 0; j < 16; ++j) {
          float dA = __expf(dtv * a[j]);
          h2[j >> 1][j & 1] = fmaf(dA, h2[j >> 1][j & 1], du * B2[j >> 1][j & 1]);
        }
      }
    }
#pragma unroll
    for (int j = 0; j < 16; ++j) {
      int o = (bc * 16 + j) * 256 + d;
      cP[o]  = f2bf(__expf(a[j] * sdt));
      cHe[o] = f2bf(h2[j >> 1][j & 1]);
    }
  }
}

// ---------------------------------------------------------------------------
// Hierarchical combine (NC=128, bf16): 512 thr = 64 sd x 8 segments of 16.
// ---------------------------------------------------------------------------
__global__ __launch_bounds__(512)
void scan_combine(unsigned short* __restrict__ cP, const unsigned short* __restrict__ cHe) {
  __shared__ float segP[64 * 9], segH[64 * 9], segS[64 * 9];
  const int t = threadIdx.x;
  const int sdl = t & 63, seg = t >> 6;
  const int blk = blockIdx.x;
  const int b = blk >> 6, grp = blk & 63;
  const int sd = (grp << 6) + sdl;
  const int base = b * NC * 4096 + sd;
  float Pacc = 1.f, Hacc = 0.f;
#pragma unroll
  for (int i = 0; i < 16; ++i) {
    int idx = base + (seg * 16 + i) * 4096;
    float p = bf2f((unsigned int)cP[idx]);
    float he = bf2f((unsigned int)cHe[idx]);
    Hacc = fmaf(p, Hacc, he);
    Pacc *= p;
  }
  segP[sdl * 9 + seg] = Pacc;
  segH[sdl * 9 + seg] = Hacc;
  __syncthreads();
  if (t < 64) {
    float hs = 0.f;
#pragma unroll
    for (int s2 = 0; s2 < 8; ++s2) {
      segS[t * 9 + s2] = hs;
      hs = fmaf(segP[t * 9 + s2], hs, segH[t * 9 + s2]);
    }
  }
  __syncthreads();
  float hs = segS[sdl * 9 + seg];
#pragma unroll
  for (int i = 0; i < 16; ++i) {
    int idx = base + (seg * 16 + i) * 4096;
    float p = bf2f((unsigned int)cP[idx]);
    float he = bf2f((unsigned int)cHe[idx]);
    cP[idx] = f2bf(hs);
    hs = fmaf(p, hs, he);
  }
}

// ---------------------------------------------------------------------------
// FUSED scan phase 3 + out_proj + LayerNorm + fc + ReLU (r10 exact:
// 8-wave epilogue, smB-staged weights, depth-2 prefetch).
// LDS: Bs 4K + Cs 4K + smA 33.8K + smB 34.8K + pS 1K = 77.6 KB -> 2 blk/CU.
// ---------------------------------------------------------------------------
__global__ __launch_bounds__(512, 4)
void scan3_out_ln_fc(const unsigned int* __restrict__ udt,
                     const float* __restrict__ Bb, const float* __restrict__ Cb,
                     const float* __restrict__ alog, const unsigned short* __restrict__ hst,
                     const float* __restrict__ dsk,
                     const unsigned short* __restrict__ zsb,
                     const unsigned short* __restrict__ ow_b,
                     const float* __restrict__ gamma, const float* __restrict__ beta,
                     const unsigned short* __restrict__ fcw_b, float* __restrict__ out) {
  __shared__ float Bs[CH2 * 16];             // 4 KB
  __shared__ float Cs[CH2 * 16];             // 4 KB
  __shared__ unsigned short smA[64 * 264];   // ya (stride 264); later hnb (stride 136)
  __shared__ unsigned short smB[128 * 136];  // ow half (stride 264); later fcw (136)
  __shared__ float pS1[128], pS2[128];       // LN cross-wave partials [np*64+row]
  const int bc = blockIdx.x;
  const int b = bc >> 6, cc = bc & 63;
  const int t = threadIdx.x;
  const int l = t & 63, w = t >> 6;
  const int chh = t >> 8;                     // which of the 2 parallel chunks
  const int d = t & 255;                      // channel
  const int base = b * L_ + (cc << 1) * CH;   // 64-position tile start
  const int cbase = base + chh * CH;          // this chunk's start
  const int hc = b * NC + (cc << 1) + chh;    // h_start chunk index
  if (t < CH2 * 4)           ((float4*)Bs)[t]            = *(const float4*)&Bb[base * 16 + (t << 2)];
  else if (t < CH2 * 8)      ((float4*)Cs)[t - CH2 * 4]  = *(const float4*)&Cb[base * 16 + ((t - CH2 * 4) << 2)];
  float a[16];
  bool okl = true;
#pragma unroll
  for (int j = 0; j < 16; ++j) {
    a[j] = -__expf(alog[d * 16 + j]);
    float tgt = (float)(j + 1);
    okl = okl && (fabsf(a[j] + tgt) <= 1e-3f * tgt);
  }
  const bool fast = (bool)__all((int)okl);
  const float dskv = dsk[d];
  f32x2 h2[8];
#pragma unroll
  for (int jj = 0; jj < 8; ++jj) {
    h2[jj][0] = bf2f((unsigned int)hst[(hc * 16 + (jj << 1)) * 256 + d]);
    h2[jj][1] = bf2f((unsigned int)hst[(hc * 16 + (jj << 1) + 1) * 256 + d]);
  }
  unsigned int wv0 = udt[cbase * 256 + d];
  unsigned int wv1 = udt[(cbase + 1) * 256 + d];
  unsigned short zv0 = zsb[cbase * 256 + d];
  unsigned short zv1 = zsb[(cbase + 1) * 256 + d];
  __syncthreads();
#pragma unroll 2
  for (int ll = 0; ll < CH; ++ll) {
    const int l2 = (ll + 2 < CH) ? ll + 2 : CH - 1;
    unsigned int wv2 = udt[(cbase + l2) * 256 + d];
    unsigned short zv2 = zsb[(cbase + l2) * 256 + d];
    const float* brow = &Bs[(chh * CH + ll) * 16];
    const float* crow = &Cs[(chh * CH + ll) * 16];
    float4 b0 = *(const float4*)&brow[0];
    float4 b1 = *(const float4*)&brow[4];
    float4 b2 = *(const float4*)&brow[8];
    float4 b3 = *(const float4*)&brow[12];
    float4 c0 = *(const float4*)&crow[0];
    float4 c1 = *(const float4*)&crow[4];
    float4 c2 = *(const float4*)&crow[8];
    float4 c3 = *(const float4*)&crow[12];
    float uv  = bf2f(wv0 & 0xFFFFu);
    float dtv = bf2f(wv0 >> 16);
    f32x2 B2[8] = {{b0.x,b0.y},{b0.z,b0.w},{b1.x,b1.y},{b1.z,b1.w},
                   {b2.x,b2.y},{b2.z,b2.w},{b3.x,b3.y},{b3.z,b3.w}};
    f32x2 C2[8] = {{c0.x,c0.y},{c0.z,c0.w},{c1.x,c1.y},{c1.z,c1.w},
                   {c2.x,c2.y},{c2.z,c2.w},{c3.x,c3.y},{c3.z,c3.w}};
    float du = dtv * uv;
    f32x2 du2 = {du, du};
    f32x2 y2 = {0.f, 0.f};
    if (fast) {
      float e1 = __expf(-dtv);
      float e2 = e1 * e1;
      f32x2 dA = {e1, e2};
      f32x2 e22 = {e2, e2};
#pragma unroll
      for (int jj = 0; jj < 8; ++jj) {
        h2[jj] = dA * h2[jj] + du2 * B2[jj];
        y2 = y2 + h2[jj] * C2[jj];
        dA = dA * e22;
      }
    } else {
#pragma unroll
      for (int j = 0; j < 16; ++j) {
        float dA = __expf(dtv * a[j]);
        float hh = fmaf(dA, h2[j >> 1][j & 1], du * B2[j >> 1][j & 1]);
        h2[j >> 1][j & 1] = hh;
        y2[j & 1] = fmaf(hh, C2[j >> 1][j & 1], y2[j & 1]);
      }
    }
    float y = y2.x + y2.y;
    float zs = bf2f((unsigned int)zv0);
    smA[(chh * CH + ll) * 264 + d] = f2bf(fmaf(uv, dskv, y) * zs);   // ya, bf16
    wv0 = wv1; wv1 = wv2; zv0 = zv1; zv1 = zv2;
  }
  // -------- epilogue (ALL 8 waves): out_proj -> LN -> fc -> ReLU --------
  const int q = l >> 4, col = l & 15;
  const int rw = w & 3, np = w >> 2;          // row-group x channel-half
  ffrag acc[2][2];
  for (int nt2 = 0; nt2 < 2; ++nt2) {
    __syncthreads();           // iter0: ya complete; iter1: prior smB reads done
    for (int i = t; i < 64 * 32; i += 512) {
      int row = i >> 5, c8 = (i & 31) << 3;
      *(uint4*)&smB[row * 264 + c8] = *(const uint4*)&ow_b[((nt2 << 6) + row) * 256 + c8];
    }
    __syncthreads();
#pragma unroll
    for (int nt = 0; nt < 2; ++nt) acc[nt2][nt] = (ffrag){0.f, 0.f, 0.f, 0.f};
#pragma unroll
    for (int s8 = 0; s8 < 8; ++s8) {
      int k0 = s8 * 32 + q * 8;
      bfrag af = *(const bfrag*)&smA[((rw << 4) + col) * 264 + k0];
#pragma unroll
      for (int nt = 0; nt < 2; ++nt) {
        bfrag bf_ = *(const bfrag*)&smB[((((np << 1) + nt) << 4) + col) * 264 + k0];
        acc[nt2][nt] = __builtin_amdgcn_mfma_f32_16x16x32_bf16(af, bf_, acc[nt2][nt], 0, 0, 0);
      }
    }
  }
  float s1v[4], s2v[4];
#pragma unroll
  for (int i = 0; i < 4; ++i) {
    float s1 = 0.f, s2 = 0.f;
#pragma unroll
    for (int nt2 = 0; nt2 < 2; ++nt2)
#pragma unroll
      for (int nt = 0; nt < 2; ++nt) {
        float v = acc[nt2][nt][i];
        s1 += v; s2 = fmaf(v, v, s2);
      }
    s1 += __shfl_xor(s1, 1); s2 += __shfl_xor(s2, 1);
    s1 += __shfl_xor(s1, 2); s2 += __shfl_xor(s2, 2);
    s1 += __shfl_xor(s1, 4); s2 += __shfl_xor(s2, 4);
    s1 += __shfl_xor(s1, 8); s2 += __shfl_xor(s2, 8);
    s1v[i] = s1; s2v[i] = s2;
  }
  if (col == 0) {
#pragma unroll
    for (int i = 0; i < 4; ++i) {
      int r = (rw << 4) + (q << 2) + i;
      pS1[(np << 6) + r] = s1v[i];
      pS2[(np << 6) + r] = s2v[i];
    }
  }
  __syncthreads();   // partials ready; all smA(ya)/smB(ow) reads done
  float mu[4], rs[4];
#pragma unroll
  for (int i = 0; i < 4; ++i) {
    int r = (rw << 4) + (q << 2) + i;
    float s1 = pS1[r] + pS1[64 + r];
    float s2 = pS2[r] + pS2[64 + r];
    mu[i] = s1 * (1.f / DM);
    float var = s2 * (1.f / DM) - mu[i] * mu[i];
    rs[i] = rsqrtf(var + 1e-5f);
  }
#pragma unroll
  for (int nt2 = 0; nt2 < 2; ++nt2)
#pragma unroll
    for (int nt = 0; nt < 2; ++nt) {
      int n = (nt2 << 6) + ((((np << 1) + nt)) << 4) + col;
      float g = gamma[n], be = beta[n];
#pragma unroll
      for (int i = 0; i < 4; ++i) {
        int r = (rw << 4) + (q << 2) + i;
        smA[r * 136 + n] = f2bf(fmaf((acc[nt2][nt][i] - mu[i]) * rs[i], g, be));
      }
    }
  for (int i = t; i < 128 * 16; i += 512) {
    int row = i >> 4, c8 = (i & 15) << 3;
    *(uint4*)&smB[row * 136 + c8] = *(const uint4*)&fcw_b[row * 128 + c8];
  }
  __syncthreads();
  ffrag a2[4] = {{0.f,0.f,0.f,0.f},{0.f,0.f,0.f,0.f},{0.f,0.f,0.f,0.f},{0.f,0.f,0.f,0.f}};
#pragma unroll
  for (int s8 = 0; s8 < 4; ++s8) {
    int k0 = s8 * 32 + q * 8;
    bfrag af = *(const bfrag*)&smA[((rw << 4) + col) * 136 + k0];
#pragma unroll
    for (int nt = 0; nt < 4; ++nt) {
      bfrag bf_ = *(const bfrag*)&smB[((((np << 2) + nt) << 4) + col) * 136 + k0];
      a2[nt] = __builtin_amdgcn_mfma_f32_16x16x32_bf16(af, bf_, a2[nt], 0, 0, 0);
    }
  }
#pragma unroll
  for (int nt = 0; nt < 4; ++nt)
#pragma unroll
    for (int i = 0; i < 4; ++i) {
      int ml = (rw << 4) + (q << 2) + i;
      out[(base + ml) * 128 + (((np << 2) + nt) << 4) + col] = fmaxf(a2[nt][i], 0.f);
    }
}

extern "C" void kernel_launch(void* const* d_in, const int* in_sizes, int n_in,
                              void* d_out, int out_size, void* d_ws, size_t ws_size,
                              hipStream_t stream) {
  (void)in_sizes; (void)n_in; (void)out_size; (void)ws_size;
  const float* s    = (const float*)d_in[0];
  const float* w_in = (const float*)d_in[1];
  const float* cw   = (const float*)d_in[2];
  const float* cb   = (const float*)d_in[3];
  const float* xw   = (const float*)d_in[4];
  const float* dtw  = (const float*)d_in[5];
  const float* dtpb = (const float*)d_in[6];
  const float* alog = (const float*)d_in[7];
  const float* dsk  = (const float*)d_in[8];
  const float* ow   = (const float*)d_in[9];
  const float* gam  = (const float*)d_in[10];
  const float* bet  = (const float*)d_in[11];
  const float* fcw  = (const float*)d_in[12];
  float* out = (float*)d_out;
  float* ws  = (float*)d_ws;

  // float-unit offsets; all regions disjoint (audited; bf16 regions sized
  // as (num bf16 values)/2 floats):
  unsigned short* zsb  = (unsigned short*)(ws + 4194304);     // [4194304, 8388608)
  unsigned int*   udt  = (unsigned int*)(ws + 8388608);       // [8388608, 16777216)
  float*          Bb   = ws + 16777216;                       // [16777216, 17301504)
  float*          Cb   = ws + 17301504;                       // [17301504, 17825792)
  unsigned short* cP   = (unsigned short*)(ws + 17825792);    // [17825792, 19922944)
  unsigned short* cHe  = (unsigned short*)(ws + 19922944);    // [19922944, 22020096)
  unsigned short* w_in_b = (unsigned short*)(ws + 22020096);  // 65536 bf16 -> [22020096, 22052864)
  unsigned short* xw_b   = (unsigned short*)(ws + 22052864);  // 10240 bf16 -> [22052864, 22057984)
  unsigned short* ow_b   = (unsigned short*)(ws + 22057984);  // 32768 bf16 -> [22057984, 22074368)
  unsigned short* fcw_b  = (unsigned short*)(ws + 22074368);  // 16384 bf16 -> [22074368, 22082560)

  // 0. one-shot weight f32->bf16 (identical RNE)
  prep_weights<<<122, 256, 0, stream>>>(w_in, xw, ow, fcw, w_in_b, xw_b, ow_b, fcw_b);
  // 1. MEGA-FUSED front end: 1024 x 256 (1 chunk/block, 4 blocks/CU)
  xproj_dtproj<<<M_ / CH, 256, 0, stream>>>(s, w_in_b, xw_b, dtw, dtpb, cw, cb, alog,
                                            Bb, Cb, udt, zsb, cP, cHe);
  // 2. inter-chunk combine
  scan_combine<<<512, 512, 0, stream>>>(cP, cHe);
  // 3. FUSED scan phase 3 + out_proj(smB-staged) + LN + fc + ReLU, 8-wave epilogue
  scan3_out_ln_fc<<<B_ * NC / 2, 512, 0, stream>>>(udt, Bb, Cb, alog, cP, dsk, zsb,
                                                   ow_b, gam, bet, fcw_b, out);
}